// Round 8
// baseline (410.724 us; speedup 1.0000x reference)
//
#include <hip/hip_runtime.h>
#include <stdint.h>

typedef __bf16 bf16;
typedef __bf16 bf16x8 __attribute__((ext_vector_type(8)));
typedef float f32x4 __attribute__((ext_vector_type(4)));

// ---------------- async global->LDS (16B per lane) ----------------
static __device__ __forceinline__ void async16(const void* g, void* l) {
  __builtin_amdgcn_global_load_lds(
      (__attribute__((address_space(1))) void*)g,
      (__attribute__((address_space(3))) void*)l, 16, 0, 0);
}

// ---------------- merged prep ----------------
// blocks [0,2048) Ttrig | [2048,11840) Atrig2 (cos|sin half-DFT, K=1088) |
// [11840,28224) cast x_dec | [28224,44608) cast x_enc | [44608,50752) weight transposes
// BtQ uses the h-in-bits-4:5 permuted row order n=(e&15)|(h<<4)|((e>>4)<<6) so the
// QKV epilogue gets h==ni (register-axis softmax). BtK/BtV keep n=4e+h.
__global__ void __launch_bounds__(256) prep_all(
    const float* __restrict__ xdec, const float* __restrict__ xenc,
    bf16* __restrict__ Ttrig, bf16* __restrict__ Atrig2,
    bf16* __restrict__ xdec_b, bf16* __restrict__ xenc_b,
    const float* __restrict__ Wq, const float* __restrict__ Wk,
    const float* __restrict__ Wv, const float* __restrict__ Wo,
    const float* __restrict__ W1, const float* __restrict__ W2,
    bf16* __restrict__ BtQ, bf16* __restrict__ BtK, bf16* __restrict__ BtV,
    bf16* __restrict__ WoTh, bf16* __restrict__ W1T, bf16* __restrict__ W2T) {
  __shared__ bf16 tile[32][33];
  int id = blockIdx.x;
  if (id < 2048) {                     // Ttrig[1024][512]
    int idx = id * 256 + threadIdx.x;
    int d = idx & 511, jp = idx >> 9;
    int jj = jp >> 1, p = jp & 1;
    int t = (d * jj) & 511;
    float ang = (float)t * (6.283185307179586f / 512.0f);
    Ttrig[idx] = (bf16)(p ? __sinf(ang) : __cosf(ang));
  } else if (id < 11840) {             // Atrig2[2][1152][1088]: half 0 cos, half 1 -sin
    int idx = (id - 2048) * 256 + threadIdx.x;   // < 2506752
    int k = idx % 1088;
    int rr = idx / 1088;
    int r = rr % 1152, half = rr / 1152;
    float v = 0.0f;
    int tt = (r * k) & 2047;
    float ang = (float)tt * (6.283185307179586f / 2048.0f);
    if (half == 0) { if (r <= 1024 && k <= 1024) v = __cosf(ang); }
    else           { if (r <= 1023 && k >= 1 && k <= 1023) v = -__sinf(ang); }
    Atrig2[idx] = (bf16)v;
  } else if (id < 28224) {
    int i = (id - 11840) * 256 + threadIdx.x;
    xdec_b[i] = (bf16)xdec[i];
  } else if (id < 44608) {
    int i = (id - 28224) * 256 + threadIdx.x;
    xenc_b[i] = (bf16)xenc[i];
  } else {
    int id2 = id - 44608;
    int kind = id2 >> 10, t = id2 & 1023;
    const float* in; bf16* out; int R, C, rt, ct;
    bool iperm = false, qperm = false, hsel = false; int hh = 0;
    if (kind == 0)      { in = Wq; out = BtQ; R = 2048; C = 512; rt = t >> 4; ct = t & 15; iperm = true; qperm = true; }
    else if (kind == 1) { in = Wk; out = BtK; R = 2048; C = 512; rt = t >> 4; ct = t & 15; iperm = true; }
    else if (kind == 2) { in = Wv; out = BtV; R = 2048; C = 512; rt = t >> 4; ct = t & 15; iperm = true; }
    else if (kind == 3) {              // WoTh[h][n][e] = Wo[4e+h][n]
      int zz = t >> 8, tt = t & 255;
      in = Wo; out = WoTh + (long)zz * 262144;
      R = 512; C = 512; rt = tt >> 4; ct = tt & 15; hsel = true; hh = zz;
    }
    else if (kind == 4) { in = W1; out = W1T; R = 512; C = 2048; rt = t >> 6; ct = t & 63; }
    else                { in = W2; out = W2T; R = 2048; C = 512; rt = t >> 4; ct = t & 15; }
    int c0 = ct * 32, r0 = rt * 32;
    int tx = threadIdx.x & 31, ty = threadIdx.x >> 5;
#pragma unroll
    for (int i = 0; i < 32; i += 8) {
      int r = r0 + ty + i;
      int rr = hsel ? (4 * r + hh) : r;
      tile[ty + i][tx] = (bf16)in[(long)rr * C + (c0 + tx)];
    }
    __syncthreads();
#pragma unroll
    for (int i = 0; i < 32; i += 8) {
      int cc = c0 + ty + i, rr = r0 + tx;
      if (iperm) {  // Bt row from W row h*512+din; cc = e, rr>>9 = h, rr&511 = din
        int e = cc, h = rr >> 9;
        int n = qperm ? ((e & 15) | (h << 4) | ((e >> 4) << 6)) : (4 * e + h);
        out[((long)n << 9) + (rr & 511)] = tile[tx][ty + i];
      } else {
        out[(long)cc * R + rr] = tile[tx][ty + i];
      }
    }
  }
}

// Fold Yt [4][512][4096] -> Yf2 [8][512][1088]: z<4 cos-fold Ycf[b], z>=4 sin-fold Ysf[b]
__global__ void __launch_bounds__(256) fold_y(const bf16* __restrict__ Yt,
                                              bf16* __restrict__ Yf2) {
  int idx = blockIdx.x * 256 + threadIdx.x;   // 8*512*1088 = 4456448
  int k = idx % 1088;
  int rr = idx / 1088;
  int j = rr & 511, z = rr >> 9;
  int b = z & 3, half = z >> 2;
  const bf16* yin = Yt + (long)b * 2097152 + (long)j * 4096;
  float v = 0.0f;
  if (half == 0) {
    if (k == 0) v = (float)yin[0];
    else if (k == 1024) v = (float)yin[1024];
    else if (k < 1024) v = (float)yin[k] + (float)yin[2048 - k];
  } else {
    if (k >= 1 && k <= 1023) v = (float)yin[2048 + k] - (float)yin[4096 - k];
  }
  Yf2[(long)z * 557056 + (long)j * 1088 + k] = (bf16)v;
}

// ---------------- LN1 with DFT recombination: xf[s] = C[s'] ± S[s'] ----------------
__global__ void __launch_bounds__(256) ln1_kernel(
    const float* __restrict__ xdec, const bf16* __restrict__ CSb,
    const float* __restrict__ g, const float* __restrict__ be,
    bf16* __restrict__ outb) {
  const int row = blockIdx.x, t = threadIdx.x;
  const int b = row >> 11, s = row & 2047;
  const int sp = (s <= 1024) ? s : 2048 - s;
  const float sgn = (s <= 1024) ? 1.0f : -1.0f;
  const bf16* Crow = CSb + ((long)b * 1152 + sp) * 512;
  const bf16* Srow = CSb + ((long)(b + 4) * 1152 + sp) * 512;
  const long base = (long)row * 512;
  float v0 = xdec[base + t] + (float)Crow[t] + sgn * (float)Srow[t];
  float v1 = xdec[base + t + 256] + (float)Crow[t + 256] + sgn * (float)Srow[t + 256];
  float sm = v0 + v1, q = v0 * v0 + v1 * v1;
#pragma unroll
  for (int off = 32; off > 0; off >>= 1) {
    sm += __shfl_down(sm, off);
    q += __shfl_down(q, off);
  }
  __shared__ float red[8];
  const int wv = t >> 6, ln = t & 63;
  if (ln == 0) { red[wv] = sm; red[wv + 4] = q; }
  __syncthreads();
  float S = red[0] + red[1] + red[2] + red[3];
  float Q = red[4] + red[5] + red[6] + red[7];
  float mu = S * (1.0f / 512.0f);
  float var = Q * (1.0f / 512.0f) - mu * mu;
  float rstd = rsqrtf(var + 1e-5f);
  outb[base + t] = (bf16)(g[t] * (v0 - mu) * rstd + be[t]);
  outb[base + t + 256] = (bf16)(g[t + 256] * (v1 - mu) * rstd + be[t + 256]);
}

// ---------------- K softmax + K/V transpose body (Q softmax fused into QKV GEMM) -------
// bid [0,1024): K -> ksT[b,h,d,s] (softmax over h + LDS transpose)
// bid [1024,2048): V -> vsT[b,h,e,s] (LDS transpose only)
static __device__ __forceinline__ void smkv_body(
    int bid, bf16* lds,
    const bf16* __restrict__ klog, bf16* __restrict__ ksT,
    const bf16* __restrict__ vlog, bf16* __restrict__ vsT) {
  const int t = threadIdx.x;
  const bool isK = bid < 1024;
  int tb = isK ? bid : (bid - 1024);  // 4b x 32 s-tiles x 8 e-tiles
  const bf16* src = isK ? klog : vlog;
  bf16* dst = isK ? ksT : vsT;
  int b = tb >> 8, rem = tb & 255;
  int s0 = (rem >> 3) << 6, e0 = (rem & 7) << 6;
  int te = t & 63, tr = t >> 6;
#pragma unroll
  for (int i = 0; i < 16; ++i) {
    int s = tr + (i << 2);
    bf16 raw[4] __attribute__((aligned(8)));
    *(uint2*)raw = *(const uint2*)(src + ((long)(b * 2048 + s0 + s) * 2048 + 4 * (e0 + te)));
    float x0 = (float)raw[0], x1 = (float)raw[1], x2 = (float)raw[2], x3 = (float)raw[3];
    if (isK) {
      float m = fmaxf(fmaxf(x0, x1), fmaxf(x2, x3));
      float y0 = __expf(x0 - m), y1 = __expf(x1 - m), y2 = __expf(x2 - m), y3 = __expf(x3 - m);
      float rs = 1.0f / (y0 + y1 + y2 + y3);
      x0 = y0 * rs; x1 = y1 * rs; x2 = y2 * rs; x3 = y3 * rs;
    }
    int cp = ((((s >> 2) ^ (te & 15)) << 2) | (s & 3));
    int base = te * 64 + cp;
    lds[base] = (bf16)x0;
    lds[4096 + base] = (bf16)x1;
    lds[8192 + base] = (bf16)x2;
    lds[12288 + base] = (bf16)x3;
  }
  __syncthreads();
  int sc = t & 15, r = t >> 4;
#pragma unroll
  for (int i = 0; i < 16; ++i) {
    int he = r + (i << 4);
    int h = he >> 6, e = he & 63;
    int cp = (sc ^ (e & 15)) << 2;
    bf16 tmp[4] __attribute__((aligned(8)));
    *(uint2*)tmp = *(const uint2*)&lds[h * 4096 + e * 64 + cp];
    *(uint2*)(dst + ((long)(b * 4 + h) * 512 + e0 + e) * 2048 + s0 + (sc << 2)) =
        *(const uint2*)tmp;
  }
}

// ---------------- generic LayerNorm ----------------
template <typename TA, typename TB, int WRITE_BF16, int WRITE_F32>
__global__ void __launch_bounds__(256) ln_kernel(
    const TA* __restrict__ A, const TB* __restrict__ Bv,
    const float* __restrict__ g, const float* __restrict__ be,
    bf16* __restrict__ outb, float* __restrict__ outf) {
  const int row = blockIdx.x, t = threadIdx.x;
  const long base = (long)row * 512;
  float v0 = (float)A[base + t] + (float)Bv[base + t];
  float v1 = (float)A[base + t + 256] + (float)Bv[base + t + 256];
  float s = v0 + v1, q = v0 * v0 + v1 * v1;
#pragma unroll
  for (int off = 32; off > 0; off >>= 1) {
    s += __shfl_down(s, off);
    q += __shfl_down(q, off);
  }
  __shared__ float red[8];
  const int wv = t >> 6, ln = t & 63;
  if (ln == 0) { red[wv] = s; red[wv + 4] = q; }
  __syncthreads();
  float S = red[0] + red[1] + red[2] + red[3];
  float Q = red[4] + red[5] + red[6] + red[7];
  float mu = S * (1.0f / 512.0f);
  float var = Q * (1.0f / 512.0f) - mu * mu;
  float rstd = rsqrtf(var + 1e-5f);
  float o0 = g[t] * (v0 - mu) * rstd + be[t];
  float o1 = g[t + 256] * (v1 - mu) * rstd + be[t + 256];
  if (WRITE_BF16) { outb[base + t] = (bf16)o0; outb[base + t + 256] = (bf16)o1; }
  if (WRITE_F32)  { outf[base + t] = o0; outf[base + t + 256] = o1; }
}

// ---------------- GEMM body: C = A[M,K] * Bt[N,K]^T (single-buffer m97 K-loop) ---------
// SWIZ: 0 plain; 1 group-by-y; 2 group-by-z; 3 group-by-x. gin = blocks per group.
// ADDR_MODE: 0 plain (sCz*z); 7 gw out h*512+col; 9 gw out (col&15)|(h<<4)|((col>>4)<<6).
// HAS_BIAS: 0 none, 1 bias[sBiasz*z+col].
// AHEAD: 0 A+=sAz*z; 1 A+=sAz*(z&3); 2 A+=sAz*(z>>2).
template <int BN, int ADDR_MODE, int HAS_BIAS, int DO_SELU, int F32OUT, int SWIZ,
          int AHEAD>
static __device__ __forceinline__ void gemm_bt_body(
    int id, bf16* lA, bf16* lB,
    const bf16* __restrict__ A, const bf16* __restrict__ Bt,
    const float* __restrict__ bias, void* __restrict__ Cout,
    int N, int K, long sAz, long sBz, long sBiasz, long sCz,
    int gx, int gy, int gin) {
  int x, y, z;
  {
    if (SWIZ == 0) {
      x = id % gx; int t2 = id / gx; y = t2 % gy; z = t2 / gy;
    } else {
      int xcd = id & 7, r = id >> 3;
      int inner = r % gin, G = xcd + 8 * (r / gin);
      if (SWIZ == 1)      { y = G; x = inner % gx; z = inner / gx; }
      else if (SWIZ == 2) { z = G; x = inner % gx; y = inner / gx; }
      else                { x = G; y = inner % gy; z = inner / gy; }
    }
  }
  A  += (AHEAD == 1) ? sAz * (z & 3) : (AHEAD == 2) ? sAz * (z >> 2) : sAz * z;
  Bt += sBz * z;
  const int m0 = y * 128, n0 = x * BN;
  const int t = threadIdx.x;
  const int lane = t & 63, wave = t >> 6;
  const int srow = t >> 3;
  const int pch  = t & 7;
  const int lch  = pch ^ (srow & 7);   // XOR bank swizzle (global-side)
  const bf16* Ag = A  + (long)(m0 + srow) * K + lch * 8;
  const bf16* Bg = Bt + (long)(n0 + srow) * K + lch * 8;
  bf16* lAp = lA + srow * 64 + pch * 8;
  bf16* lBp = lB + srow * 64 + pch * 8;
  constexpr int MI = (BN == 128) ? 4 : 2;
  const int wm = (BN == 128) ? (wave >> 1) * 64 : wave * 32;
  const int wn = (BN == 128) ? (wave & 1) * 64 : 0;
  const int fr = lane & 15, fq = lane >> 4;

  f32x4 acc[MI][4] = {};

  for (int k0 = 0; k0 < K; k0 += 64) {
    __syncthreads();
#pragma unroll
    for (int i = 0; i < 4; ++i)
      async16(Ag + k0 + (long)(32 * i) * K, lAp + 32 * i * 64);
#pragma unroll
    for (int i = 0; i < BN / 32; ++i)
      async16(Bg + k0 + (long)(32 * i) * K, lBp + 32 * i * 64);
    __syncthreads();
#pragma unroll
    for (int kk = 0; kk < 2; ++kk) {
      bf16x8 av[MI], bfrag[4];
#pragma unroll
      for (int mi = 0; mi < MI; ++mi) {
        int r = wm + mi * 16 + fr;
        int c = (kk * 4 + fq) ^ (r & 7);
        av[mi] = *(const bf16x8*)&lA[r * 64 + c * 8];
      }
#pragma unroll
      for (int ni = 0; ni < 4; ++ni) {
        int r = wn + ni * 16 + fr;
        int c = (kk * 4 + fq) ^ (r & 7);
        bfrag[ni] = *(const bf16x8*)&lB[r * 64 + c * 8];
      }
#pragma unroll
      for (int mi = 0; mi < MI; ++mi)
#pragma unroll
        for (int ni = 0; ni < 4; ++ni)
          acc[mi][ni] = __builtin_amdgcn_mfma_f32_16x16x32_bf16(
              av[mi], bfrag[ni], acc[mi][ni], 0, 0, 0);
    }
  }

  // epilogue: C/D layout col = lane&15, row = (lane>>4)*4 + reg
#pragma unroll
  for (int mi = 0; mi < MI; ++mi) {
#pragma unroll
    for (int ni = 0; ni < 4; ++ni) {
      const int col = n0 + wn + ni * 16 + fr;
      float bias_v = 0.0f;
      if (HAS_BIAS == 1) bias_v = bias[sBiasz * z + col];
      if (ADDR_MODE == 7) {                  // z=b*4+h -> Bt_b[n=row][h*512+col]
        const int b = z >> 2, h = z & 3;
#pragma unroll
        for (int r = 0; r < 4; ++r) {
          const int row = m0 + wm + mi * 16 + fq * 4 + r;
          ((bf16*)Cout)[((long)(b * 512 + row)) * 2048 + h * 512 + col] =
              (bf16)(acc[mi][ni][r] + bias_v);
        }
      } else if (ADDR_MODE == 9) {           // z=b*4+h -> Bt_b[row][(col&15)|(h<<4)|((col>>4)<<6)]
        const int b = z >> 2, h = z & 3;
        const int kidx = (col & 15) | (h << 4) | ((col >> 4) << 6);
#pragma unroll
        for (int r = 0; r < 4; ++r) {
          const int row = m0 + wm + mi * 16 + fq * 4 + r;
          ((bf16*)Cout)[((long)(b * 512 + row)) * 2048 + kidx] =
              (bf16)(acc[mi][ni][r] + bias_v);
        }
      } else {
#pragma unroll
        for (int r = 0; r < 4; ++r) {
          const int row = m0 + wm + mi * 16 + fq * 4 + r;
          float v = acc[mi][ni][r] + bias_v;
          if (DO_SELU) v = v > 0.0f ? 1.0507009873554805f * v
                                    : 1.7580993408473766f * (__expf(v) - 1.0f);
          long addr = sCz * z + (long)row * N + col;
          if (F32OUT) ((float*)Cout)[addr] = v;
          else        ((bf16*)Cout)[addr] = (bf16)v;
        }
      }
    }
  }
}

// standalone wrapper
template <int BN, int ADDR_MODE, int HAS_BIAS, int DO_SELU, int F32OUT, int SWIZ,
          int AHEAD = 0>
__global__ void __launch_bounds__(256, 2) gemm_bt(
    const bf16* __restrict__ A, const bf16* __restrict__ Bt,
    const float* __restrict__ bias, void* __restrict__ Cout,
    int N, int K, long sAz, long sBz, long sBiasz, long sCz,
    int gx, int gy, int gin) {
  __shared__ __align__(16) bf16 lA[128 * 64];
  __shared__ __align__(16) bf16 lB[BN * 64];
  gemm_bt_body<BN, ADDR_MODE, HAS_BIAS, DO_SELU, F32OUT, SWIZ, AHEAD>(
      blockIdx.x, lA, lB, A, Bt, bias, Cout, N, K, sAz, sBz, sBiasz, sCz, gx, gy, gin);
}

// ---------------- Q/K/V projection GEMM body (id in [0,3072), uniform segments) --------
// seg 1/2 (K,V): out[b,s,4e+h] interleaved, coalesced writes.
// seg 0 (Q): BtQ row order puts h in col bits 4:5 -> h == ni in the epilogue, so the
// head-softmax is PURE REGISTER math across the 4 ni accumulators (no shuffles).
// qs2 K-index layout: kidx = (d&15)|(h<<4)|((d>>4)<<6) — matched by gwT (ADDR_MODE 9).
static __device__ __forceinline__ void qkv_body(
    int id, bf16* lA, bf16* lB,
    const bf16* __restrict__ Aq, const bf16* __restrict__ Aenc,
    const bf16* __restrict__ BQ, const bf16* __restrict__ BK,
    const bf16* __restrict__ BV,
    const float* __restrict__ bq, const float* __restrict__ bk,
    const float* __restrict__ bv,
    bf16* __restrict__ qs2, bf16* __restrict__ klog, bf16* __restrict__ vlog) {
  const int seg = id >> 10, sid = id & 1023;
  const int xcd = sid & 7, r = sid >> 3;
  const int x = r & 15, y = xcd + 8 * (r >> 4);
  const bf16 *A, *Bt; bf16* out; const float* bias;
  if (seg == 0)      { A = Aq;   Bt = BQ; out = qs2;  bias = bq; }
  else if (seg == 1) { A = Aenc; Bt = BK; out = klog; bias = bk; }
  else               { A = Aenc; Bt = BV; out = vlog; bias = bv; }
  const int K = 512;
  const int m0 = y * 128, n0 = x * 128;
  const int t = threadIdx.x;
  const int lane = t & 63, wave = t >> 6;
  const int srow = t >> 3, pch = t & 7, lch = pch ^ (srow & 7);
  const bf16* Ag = A  + (long)(m0 + srow) * K + lch * 8;
  const bf16* Bg = Bt + (long)(n0 + srow) * K + lch * 8;
  bf16* lAp = lA + srow * 64 + pch * 8;
  bf16* lBp = lB + srow * 64 + pch * 8;
  const int wm = (wave >> 1) * 64, wn = (wave & 1) * 64;
  const int fr = lane & 15, fq = lane >> 4;

  f32x4 acc[4][4] = {};
  for (int k0 = 0; k0 < K; k0 += 64) {
    __syncthreads();
#pragma unroll
    for (int i = 0; i < 4; ++i) {
      async16(Ag + k0 + (long)(32 * i) * K, lAp + 32 * i * 64);
      async16(Bg + k0 + (long)(32 * i) * K, lBp + 32 * i * 64);
    }
    __syncthreads();
#pragma unroll
    for (int kk = 0; kk < 2; ++kk) {
      bf16x8 av[4], bfrag[4];
#pragma unroll
      for (int mi = 0; mi < 4; ++mi) {
        int rr = wm + mi * 16 + fr;
        int c = (kk * 4 + fq) ^ (rr & 7);
        av[mi] = *(const bf16x8*)&lA[rr * 64 + c * 8];
      }
#pragma unroll
      for (int ni = 0; ni < 4; ++ni) {
        int rr = wn + ni * 16 + fr;
        int c = (kk * 4 + fq) ^ (rr & 7);
        bfrag[ni] = *(const bf16x8*)&lB[rr * 64 + c * 8];
      }
#pragma unroll
      for (int mi = 0; mi < 4; ++mi)
#pragma unroll
        for (int ni = 0; ni < 4; ++ni)
          acc[mi][ni] = __builtin_amdgcn_mfma_f32_16x16x32_bf16(
              av[mi], bfrag[ni], acc[mi][ni], 0, 0, 0);
    }
  }

  if (seg == 0) {
    // h == ni; e = fr + 16*((n0+wn)>>6). Softmax across ni in registers.
    const int ebase = fr + 16 * ((n0 + wn) >> 6);
    const float b0 = bias[ebase], b1 = bias[512 + ebase],
                b2 = bias[1024 + ebase], b3 = bias[1536 + ebase];
#pragma unroll
    for (int mi = 0; mi < 4; ++mi) {
#pragma unroll
      for (int r = 0; r < 4; ++r) {
        const int row = m0 + wm + mi * 16 + fq * 4 + r;
        float v0 = acc[mi][0][r] + b0;
        float v1 = acc[mi][1][r] + b1;
        float v2 = acc[mi][2][r] + b2;
        float v3 = acc[mi][3][r] + b3;
        float m = fmaxf(fmaxf(v0, v1), fmaxf(v2, v3));
        float p0 = __expf(v0 - m), p1 = __expf(v1 - m),
              p2 = __expf(v2 - m), p3 = __expf(v3 - m);
        float rs = 1.0f / (p0 + p1 + p2 + p3);
        const long ob = (long)row * 2048 + n0 + wn + fr;
        out[ob]      = (bf16)(p0 * rs);
        out[ob + 16] = (bf16)(p1 * rs);
        out[ob + 32] = (bf16)(p2 * rs);
        out[ob + 48] = (bf16)(p3 * rs);
      }
    }
  } else {
#pragma unroll
    for (int mi = 0; mi < 4; ++mi) {
#pragma unroll
      for (int ni = 0; ni < 4; ++ni) {
        const int col = n0 + wn + ni * 16 + fr;
        const float bias_v = bias[(col & 3) * 512 + (col >> 2)];
#pragma unroll
        for (int r = 0; r < 4; ++r) {
          const int row = m0 + wm + mi * 16 + fq * 4 + r;
          out[(long)row * 2048 + col] = (bf16)(acc[mi][ni][r] + bias_v);
        }
      }
    }
  }
}

// ---------------- fused launches (fill CUs with independent work, fewer gaps) ----------
// [0,2048): K/V projection (qkv ids 1024..3071) | [2048,2560): Yt DFT GEMM
__global__ void __launch_bounds__(256, 2) fused_kv_yt(
    const bf16* __restrict__ Aenc, const bf16* __restrict__ BK,
    const bf16* __restrict__ BV,
    const float* __restrict__ bk, const float* __restrict__ bv,
    bf16* __restrict__ klog, bf16* __restrict__ vlog,
    const bf16* __restrict__ Ttrig, const bf16* __restrict__ xdec_b,
    bf16* __restrict__ Yt) {
  __shared__ __align__(16) bf16 smem[16384];   // 32 KiB
  int id = blockIdx.x;
  if (id < 2048)
    qkv_body(id + 1024, smem, smem + 8192, nullptr, Aenc, nullptr, BK, BV,
             nullptr, bk, bv, nullptr, klog, vlog);
  else
    gemm_bt_body<128, 0, 0, 0, 0, 3, 0>(id - 2048, smem, smem + 8192,
        Ttrig, xdec_b, nullptr, Yt, 2048, 512, 0L, 1048576L, 0L, 2097152L, 16, 8, 32);
}

// [0,2048): K/V softmax+transpose | [2048,2624): CS GEMM
__global__ void __launch_bounds__(256, 2) fused_cs_smkv(
    const bf16* __restrict__ klog, bf16* __restrict__ ksT,
    const bf16* __restrict__ vlog, bf16* __restrict__ vsT,
    const bf16* __restrict__ Atrig2, const bf16* __restrict__ Yf2,
    bf16* __restrict__ CSb) {
  __shared__ __align__(16) bf16 smem[16384];   // 32 KiB
  int id = blockIdx.x;
  if (id < 2048)
    smkv_body(id, smem, klog, ksT, vlog, vsT);
  else
    gemm_bt_body<64, 0, 0, 0, 0, 2, 2>(id - 2048, smem, smem + 8192,
        Atrig2, Yf2, nullptr, CSb, 512, 1088, 1253376L, 557056L, 0L, 589824L, 8, 9, 72);
}

// [0,1024): Q projection + head-softmax | [1024,1536): gc GEMM
__global__ void __launch_bounds__(256, 2) fused_q_gc(
    const bf16* __restrict__ Aq, const bf16* __restrict__ BQ,
    const float* __restrict__ bq, bf16* __restrict__ qs2,
    const bf16* __restrict__ ksT, const bf16* __restrict__ vsT,
    bf16* __restrict__ gc) {
  __shared__ __align__(16) bf16 smem[16384];   // 32 KiB
  int id = blockIdx.x;
  if (id < 1024)
    qkv_body(id, smem, smem + 8192, Aq, nullptr, BQ, nullptr, nullptr,
             bq, nullptr, nullptr, qs2, nullptr, nullptr);
  else
    gemm_bt_body<64, 0, 0, 0, 0, 2, 0>(id - 1024, smem, smem + 8192,
        ksT, vsT, nullptr, gc, 512, 2048, 1048576L, 1048576L, 0L, 262144L, 8, 4, 32);
}

// ---------------- launcher ----------------
extern "C" void kernel_launch(void* const* d_in, const int* in_sizes, int n_in,
                              void* d_out, int out_size, void* d_ws, size_t ws_size,
                              hipStream_t stream) {
  (void)in_sizes; (void)n_in; (void)out_size; (void)ws_size;
  const float* x_enc = (const float*)d_in[0];
  const float* x_dec = (const float*)d_in[1];
  const float* Wq = (const float*)d_in[2];
  const float* bq = (const float*)d_in[3];
  const float* Wk = (const float*)d_in[4];
  const float* bk = (const float*)d_in[5];
  const float* Wv = (const float*)d_in[6];
  const float* bv = (const float*)d_in[7];
  const float* Wo = (const float*)d_in[8];
  const float* bo = (const float*)d_in[9];
  const float* g1 = (const float*)d_in[10];
  const float* be1 = (const float*)d_in[11];
  const float* g2 = (const float*)d_in[12];
  const float* be2 = (const float*)d_in[13];
  const float* W1 = (const float*)d_in[14];
  const float* b1 = (const float*)d_in[15];
  const float* W2 = (const float*)d_in[16];
  const float* b2 = (const float*)d_in[17];
  const float* g3 = (const float*)d_in[18];
  const float* be3 = (const float*)d_in[19];

  char* ws = (char*)d_ws;
  const size_t MB = 1u << 20;
  // time-disjoint aliasing, peak 255 MiB.
  // NOTE: BtQ lives at [0,2) — it must survive until fused_q_gc (L6); its old slot
  // inside [128,160) is clobbered by ksT at L4. midb (same slot) is written at L10.
  bf16*  BtQ    = (bf16*) (ws + 0);        // [0,2) written L1, read L6
  bf16*  midb   = (bf16*) (ws + 0);        // W1 out, written L10
  bf16*  klog   = (bf16*) (ws + 32 * MB);  // written L2, dead after L4
  bf16*  attn_b = (bf16*) (ws + 32 * MB);  // attn GEMM out (L8)
  bf16*  vlog   = (bf16*) (ws + 64 * MB);  // written L2, dead after L4
  bf16*  gc     = (bf16*) (ws + 64 * MB);  // gc out (L6)
  bf16*  ff_b   = (bf16*) (ws + 72 * MB);  // W2 out
  bf16*  Atrig2 = (bf16*) (ws + 96 * MB);  // [96,101) dead after L4 (CS)
  bf16*  Ttrig  = (bf16*) (ws + 101 * MB); // [101,102) dead after L2 (Yt)
  bf16*  CSb    = (bf16*) (ws + 102 * MB); // [102,112) dead after L5 (ln1)
  bf16*  qs2    = (bf16*) (ws + 96 * MB);  // [96,128) written L6 (softmaxed Q)
  bf16*  xenc_b = (bf16*) (ws + 128 * MB); // [128,136) dead after L2
  bf16*  BtK    = (bf16*) (ws + 136 * MB); // [136,138) dead after L2
  bf16*  BtV    = (bf16*) (ws + 138 * MB); // [138,140) dead after L2
  bf16*  ksT    = (bf16*) (ws + 128 * MB); // [128,160) written L4
  bf16*  vsT    = (bf16*) (ws + 160 * MB); // [160,192) written L4
  bf16*  xd_b   = (bf16*) (ws + 192 * MB); // [192,200) written L5
  bf16*  x2_b   = (bf16*) (ws + 200 * MB); // [200,208) written L9
  bf16*  gwT    = (bf16*) (ws + 208 * MB); // [208,216) written L7
  bf16*  Yt     = (bf16*) (ws + 216 * MB); // [216,232) dead after L3 (fold)
  bf16*  Yf2    = (bf16*) (ws + 232 * MB); // [232,241) dead after L4 (CS)
  bf16*  WoTh   = (bf16*) (ws + 241 * MB); // [241,243)
  bf16*  W1T    = (bf16*) (ws + 243 * MB);
  bf16*  W2T    = (bf16*) (ws + 245 * MB);
  bf16*  xdec_b = (bf16*) (ws + 247 * MB); // [247,255) dead after L2 (Yt)

  // --- L1: prep (one launch) ---
  prep_all<<<50752, 256, 0, stream>>>(x_dec, x_enc, Ttrig, Atrig2, xdec_b, xenc_b,
                                      Wq, Wk, Wv, Wo, W1, W2,
                                      BtQ, BtK, BtV, WoTh, W1T, W2T);

  // --- L2: K/V projection  ∥  Yt DFT GEMM ---
  fused_kv_yt<<<2560, 256, 0, stream>>>(xenc_b, BtK, BtV, bk, bv, klog, vlog,
                                        Ttrig, xdec_b, Yt);

  // --- L3: fold ---
  fold_y<<<17408, 256, 0, stream>>>(Yt, Yf2);

  // --- L4: K/V softmax+transpose  ∥  CS GEMM ---
  fused_cs_smkv<<<2624, 256, 0, stream>>>(klog, ksT, vlog, vsT, Atrig2, Yf2, CSb);

  // --- L5: LN1 ---
  ln1_kernel<<<8192, 256, 0, stream>>>(x_dec, CSb, g1, be1, xd_b);

  // --- L6: Q projection+softmax  ∥  gc GEMM ---
  fused_q_gc<<<1536, 256, 0, stream>>>(xd_b, BtQ, bq, qs2, ksT, vsT, gc);

  // --- L7: gwT (permuted kidx layout) ---
  gemm_bt<64, 9, 0, 0, 0, 2, 1><<<512, 256, 0, stream>>>(
      WoTh, gc, nullptr, gwT, 512, 512, 262144L, 262144L, 0L, 0L, 8, 4, 32);
  // --- L8: attn = qs2 . gwT^T + bo ---
  gemm_bt<64, 0, 1, 0, 0, 1><<<512, 256, 0, stream>>>(
      qs2, gwT, bo, attn_b, 512, 2048, 4194304L, 1048576L, 0L, 1048576L, 8, 16, 32);
  // --- L9: LN2 ---
  ln_kernel<bf16, bf16, 1, 0><<<8192, 256, 0, stream>>>(
      xd_b, attn_b, g2, be2, x2_b, nullptr);

  // --- L10: FFN W1 + SELU ---
  gemm_bt<128, 0, 1, 1, 0, 1><<<1024, 256, 0, stream>>>(
      x2_b, W1T, b1, midb, 2048, 512, 0L, 0L, 0L, 0L, 16, 64, 16);
  // --- L11: FFN W2 ---
  gemm_bt<64, 0, 1, 0, 0, 1><<<512, 256, 0, stream>>>(
      midb, W2T, b2, ff_b, 512, 2048, 0L, 0L, 0L, 0L, 8, 64, 8);
  // --- L12: LN3 -> output (f32) ---
  ln_kernel<bf16, bf16, 0, 1><<<8192, 256, 0, stream>>>(
      x2_b, ff_b, g3, be3, nullptr, (float*)d_out);
}

// Round 9
// 381.940 us; speedup vs baseline: 1.0754x; 1.0754x over previous
//
#include <hip/hip_runtime.h>
#include <stdint.h>

typedef __bf16 bf16;
typedef __bf16 bf16x8 __attribute__((ext_vector_type(8)));
typedef float f32x4 __attribute__((ext_vector_type(4)));

// ---------------- async global->LDS (16B per lane) ----------------
static __device__ __forceinline__ void async16(const void* g, void* l) {
  __builtin_amdgcn_global_load_lds(
      (__attribute__((address_space(1))) void*)g,
      (__attribute__((address_space(3))) void*)l, 16, 0, 0);
}

// ---------------- merged prep ----------------
// blocks [0,2048) Ttrig | [2048,11840) Atrig2 (cos|sin half-DFT, K=1088) |
// [11840,28224) cast x_dec | [28224,44608) cast x_enc | [44608,50752) weight transposes
// BtQ/BtK/BtV ALL use the h-in-bits-4:5 permuted row order n=(e&15)|(h<<4)|((e>>4)<<6)
// so the QKV epilogue gets h==ni: register-axis softmax (Q,K) and register-local
// transposed stores (K,V) — the separate K/V softmax/transpose pass is eliminated.
__global__ void __launch_bounds__(256) prep_all(
    const float* __restrict__ xdec, const float* __restrict__ xenc,
    bf16* __restrict__ Ttrig, bf16* __restrict__ Atrig2,
    bf16* __restrict__ xdec_b, bf16* __restrict__ xenc_b,
    const float* __restrict__ Wq, const float* __restrict__ Wk,
    const float* __restrict__ Wv, const float* __restrict__ Wo,
    const float* __restrict__ W1, const float* __restrict__ W2,
    bf16* __restrict__ BtQ, bf16* __restrict__ BtK, bf16* __restrict__ BtV,
    bf16* __restrict__ WoTh, bf16* __restrict__ W1T, bf16* __restrict__ W2T) {
  __shared__ bf16 tile[32][33];
  int id = blockIdx.x;
  if (id < 2048) {                     // Ttrig[1024][512]
    int idx = id * 256 + threadIdx.x;
    int d = idx & 511, jp = idx >> 9;
    int jj = jp >> 1, p = jp & 1;
    int t = (d * jj) & 511;
    float ang = (float)t * (6.283185307179586f / 512.0f);
    Ttrig[idx] = (bf16)(p ? __sinf(ang) : __cosf(ang));
  } else if (id < 11840) {             // Atrig2[2][1152][1088]: half 0 cos, half 1 -sin
    int idx = (id - 2048) * 256 + threadIdx.x;   // < 2506752
    int k = idx % 1088;
    int rr = idx / 1088;
    int r = rr % 1152, half = rr / 1152;
    float v = 0.0f;
    int tt = (r * k) & 2047;
    float ang = (float)tt * (6.283185307179586f / 2048.0f);
    if (half == 0) { if (r <= 1024 && k <= 1024) v = __cosf(ang); }
    else           { if (r <= 1023 && k >= 1 && k <= 1023) v = -__sinf(ang); }
    Atrig2[idx] = (bf16)v;
  } else if (id < 28224) {
    int i = (id - 11840) * 256 + threadIdx.x;
    xdec_b[i] = (bf16)xdec[i];
  } else if (id < 44608) {
    int i = (id - 28224) * 256 + threadIdx.x;
    xenc_b[i] = (bf16)xenc[i];
  } else {
    int id2 = id - 44608;
    int kind = id2 >> 10, t = id2 & 1023;
    const float* in; bf16* out; int R, C, rt, ct;
    bool iperm = false, hsel = false; int hh = 0;
    if (kind == 0)      { in = Wq; out = BtQ; R = 2048; C = 512; rt = t >> 4; ct = t & 15; iperm = true; }
    else if (kind == 1) { in = Wk; out = BtK; R = 2048; C = 512; rt = t >> 4; ct = t & 15; iperm = true; }
    else if (kind == 2) { in = Wv; out = BtV; R = 2048; C = 512; rt = t >> 4; ct = t & 15; iperm = true; }
    else if (kind == 3) {              // WoTh[h][n][e] = Wo[4e+h][n]
      int zz = t >> 8, tt = t & 255;
      in = Wo; out = WoTh + (long)zz * 262144;
      R = 512; C = 512; rt = tt >> 4; ct = tt & 15; hsel = true; hh = zz;
    }
    else if (kind == 4) { in = W1; out = W1T; R = 512; C = 2048; rt = t >> 6; ct = t & 63; }
    else                { in = W2; out = W2T; R = 2048; C = 512; rt = t >> 4; ct = t & 15; }
    int c0 = ct * 32, r0 = rt * 32;
    int tx = threadIdx.x & 31, ty = threadIdx.x >> 5;
#pragma unroll
    for (int i = 0; i < 32; i += 8) {
      int r = r0 + ty + i;
      int rr = hsel ? (4 * r + hh) : r;
      tile[ty + i][tx] = (bf16)in[(long)rr * C + (c0 + tx)];
    }
    __syncthreads();
#pragma unroll
    for (int i = 0; i < 32; i += 8) {
      int cc = c0 + ty + i, rr = r0 + tx;
      if (iperm) {  // Bt row from W row h*512+din; cc = e, rr>>9 = h, rr&511 = din
        int e = cc, h = rr >> 9;
        int n = (e & 15) | (h << 4) | ((e >> 4) << 6);
        out[((long)n << 9) + (rr & 511)] = tile[tx][ty + i];
      } else {
        out[(long)cc * R + rr] = tile[tx][ty + i];
      }
    }
  }
}

// Fold Yt [4][512][4096] -> Yf2 [8][512][1088]: z<4 cos-fold Ycf[b], z>=4 sin-fold Ysf[b]
__global__ void __launch_bounds__(256) fold_y(const bf16* __restrict__ Yt,
                                              bf16* __restrict__ Yf2) {
  int idx = blockIdx.x * 256 + threadIdx.x;   // 8*512*1088 = 4456448
  int k = idx % 1088;
  int rr = idx / 1088;
  int j = rr & 511, z = rr >> 9;
  int b = z & 3, half = z >> 2;
  const bf16* yin = Yt + (long)b * 2097152 + (long)j * 4096;
  float v = 0.0f;
  if (half == 0) {
    if (k == 0) v = (float)yin[0];
    else if (k == 1024) v = (float)yin[1024];
    else if (k < 1024) v = (float)yin[k] + (float)yin[2048 - k];
  } else {
    if (k >= 1 && k <= 1023) v = (float)yin[2048 + k] - (float)yin[4096 - k];
  }
  Yf2[(long)z * 557056 + (long)j * 1088 + k] = (bf16)v;
}

// ---------------- LN1 with DFT recombination: xf[s] = C[s'] ± S[s'] ----------------
__global__ void __launch_bounds__(256) ln1_kernel(
    const float* __restrict__ xdec, const bf16* __restrict__ CSb,
    const float* __restrict__ g, const float* __restrict__ be,
    bf16* __restrict__ outb) {
  const int row = blockIdx.x, t = threadIdx.x;
  const int b = row >> 11, s = row & 2047;
  const int sp = (s <= 1024) ? s : 2048 - s;
  const float sgn = (s <= 1024) ? 1.0f : -1.0f;
  const bf16* Crow = CSb + ((long)b * 1152 + sp) * 512;
  const bf16* Srow = CSb + ((long)(b + 4) * 1152 + sp) * 512;
  const long base = (long)row * 512;
  float v0 = xdec[base + t] + (float)Crow[t] + sgn * (float)Srow[t];
  float v1 = xdec[base + t + 256] + (float)Crow[t + 256] + sgn * (float)Srow[t + 256];
  float sm = v0 + v1, q = v0 * v0 + v1 * v1;
#pragma unroll
  for (int off = 32; off > 0; off >>= 1) {
    sm += __shfl_down(sm, off);
    q += __shfl_down(q, off);
  }
  __shared__ float red[8];
  const int wv = t >> 6, ln = t & 63;
  if (ln == 0) { red[wv] = sm; red[wv + 4] = q; }
  __syncthreads();
  float S = red[0] + red[1] + red[2] + red[3];
  float Q = red[4] + red[5] + red[6] + red[7];
  float mu = S * (1.0f / 512.0f);
  float var = Q * (1.0f / 512.0f) - mu * mu;
  float rstd = rsqrtf(var + 1e-5f);
  outb[base + t] = (bf16)(g[t] * (v0 - mu) * rstd + be[t]);
  outb[base + t + 256] = (bf16)(g[t + 256] * (v1 - mu) * rstd + be[t + 256]);
}

// ---------------- generic LayerNorm ----------------
template <typename TA, typename TB, int WRITE_BF16, int WRITE_F32>
__global__ void __launch_bounds__(256) ln_kernel(
    const TA* __restrict__ A, const TB* __restrict__ Bv,
    const float* __restrict__ g, const float* __restrict__ be,
    bf16* __restrict__ outb, float* __restrict__ outf) {
  const int row = blockIdx.x, t = threadIdx.x;
  const long base = (long)row * 512;
  float v0 = (float)A[base + t] + (float)Bv[base + t];
  float v1 = (float)A[base + t + 256] + (float)Bv[base + t + 256];
  float s = v0 + v1, q = v0 * v0 + v1 * v1;
#pragma unroll
  for (int off = 32; off > 0; off >>= 1) {
    s += __shfl_down(s, off);
    q += __shfl_down(q, off);
  }
  __shared__ float red[8];
  const int wv = t >> 6, ln = t & 63;
  if (ln == 0) { red[wv] = s; red[wv + 4] = q; }
  __syncthreads();
  float S = red[0] + red[1] + red[2] + red[3];
  float Q = red[4] + red[5] + red[6] + red[7];
  float mu = S * (1.0f / 512.0f);
  float var = Q * (1.0f / 512.0f) - mu * mu;
  float rstd = rsqrtf(var + 1e-5f);
  float o0 = g[t] * (v0 - mu) * rstd + be[t];
  float o1 = g[t + 256] * (v1 - mu) * rstd + be[t + 256];
  if (WRITE_BF16) { outb[base + t] = (bf16)o0; outb[base + t + 256] = (bf16)o1; }
  if (WRITE_F32)  { outf[base + t] = o0; outf[base + t + 256] = o1; }
}

// ---------------- GEMM body: C = A[M,K] * Bt[N,K]^T (single-buffer m97 K-loop) ---------
// SWIZ: 0 plain; 1 group-by-y; 2 group-by-z; 3 group-by-x. gin = blocks per group.
// ADDR_MODE: 0 plain (sCz*z); 9 gw out (col&15)|(h<<4)|((col>>4)<<6).
// HAS_BIAS: 0 none, 1 bias[sBiasz*z+col].
// AHEAD: 0 A+=sAz*z; 1 A+=sAz*(z&3); 2 A+=sAz*(z>>2).
template <int BN, int ADDR_MODE, int HAS_BIAS, int DO_SELU, int F32OUT, int SWIZ,
          int AHEAD>
static __device__ __forceinline__ void gemm_bt_body(
    int id, bf16* lA, bf16* lB,
    const bf16* __restrict__ A, const bf16* __restrict__ Bt,
    const float* __restrict__ bias, void* __restrict__ Cout,
    int N, int K, long sAz, long sBz, long sBiasz, long sCz,
    int gx, int gy, int gin) {
  int x, y, z;
  {
    if (SWIZ == 0) {
      x = id % gx; int t2 = id / gx; y = t2 % gy; z = t2 / gy;
    } else {
      int xcd = id & 7, r = id >> 3;
      int inner = r % gin, G = xcd + 8 * (r / gin);
      if (SWIZ == 1)      { y = G; x = inner % gx; z = inner / gx; }
      else if (SWIZ == 2) { z = G; x = inner % gx; y = inner / gx; }
      else                { x = G; y = inner % gy; z = inner / gy; }
    }
  }
  A  += (AHEAD == 1) ? sAz * (z & 3) : (AHEAD == 2) ? sAz * (z >> 2) : sAz * z;
  Bt += sBz * z;
  const int m0 = y * 128, n0 = x * BN;
  const int t = threadIdx.x;
  const int lane = t & 63, wave = t >> 6;
  const int srow = t >> 3;
  const int pch  = t & 7;
  const int lch  = pch ^ (srow & 7);   // XOR bank swizzle (global-side)
  const bf16* Ag = A  + (long)(m0 + srow) * K + lch * 8;
  const bf16* Bg = Bt + (long)(n0 + srow) * K + lch * 8;
  bf16* lAp = lA + srow * 64 + pch * 8;
  bf16* lBp = lB + srow * 64 + pch * 8;
  constexpr int MI = (BN == 128) ? 4 : 2;
  const int wm = (BN == 128) ? (wave >> 1) * 64 : wave * 32;
  const int wn = (BN == 128) ? (wave & 1) * 64 : 0;
  const int fr = lane & 15, fq = lane >> 4;

  f32x4 acc[MI][4] = {};

  for (int k0 = 0; k0 < K; k0 += 64) {
    __syncthreads();
#pragma unroll
    for (int i = 0; i < 4; ++i)
      async16(Ag + k0 + (long)(32 * i) * K, lAp + 32 * i * 64);
#pragma unroll
    for (int i = 0; i < BN / 32; ++i)
      async16(Bg + k0 + (long)(32 * i) * K, lBp + 32 * i * 64);
    __syncthreads();
#pragma unroll
    for (int kk = 0; kk < 2; ++kk) {
      bf16x8 av[MI], bfrag[4];
#pragma unroll
      for (int mi = 0; mi < MI; ++mi) {
        int r = wm + mi * 16 + fr;
        int c = (kk * 4 + fq) ^ (r & 7);
        av[mi] = *(const bf16x8*)&lA[r * 64 + c * 8];
      }
#pragma unroll
      for (int ni = 0; ni < 4; ++ni) {
        int r = wn + ni * 16 + fr;
        int c = (kk * 4 + fq) ^ (r & 7);
        bfrag[ni] = *(const bf16x8*)&lB[r * 64 + c * 8];
      }
#pragma unroll
      for (int mi = 0; mi < MI; ++mi)
#pragma unroll
        for (int ni = 0; ni < 4; ++ni)
          acc[mi][ni] = __builtin_amdgcn_mfma_f32_16x16x32_bf16(
              av[mi], bfrag[ni], acc[mi][ni], 0, 0, 0);
    }
  }

  // epilogue: C/D layout col = lane&15, row = (lane>>4)*4 + reg
#pragma unroll
  for (int mi = 0; mi < MI; ++mi) {
#pragma unroll
    for (int ni = 0; ni < 4; ++ni) {
      const int col = n0 + wn + ni * 16 + fr;
      float bias_v = 0.0f;
      if (HAS_BIAS == 1) bias_v = bias[sBiasz * z + col];
      if (ADDR_MODE == 9) {                  // z=b*4+h -> Bt_b[row][(col&15)|(h<<4)|((col>>4)<<6)]
        const int b = z >> 2, h = z & 3;
        const int kidx = (col & 15) | (h << 4) | ((col >> 4) << 6);
#pragma unroll
        for (int r = 0; r < 4; ++r) {
          const int row = m0 + wm + mi * 16 + fq * 4 + r;
          ((bf16*)Cout)[((long)(b * 512 + row)) * 2048 + kidx] =
              (bf16)(acc[mi][ni][r] + bias_v);
        }
      } else {
#pragma unroll
        for (int r = 0; r < 4; ++r) {
          const int row = m0 + wm + mi * 16 + fq * 4 + r;
          float v = acc[mi][ni][r] + bias_v;
          if (DO_SELU) v = v > 0.0f ? 1.0507009873554805f * v
                                    : 1.7580993408473766f * (__expf(v) - 1.0f);
          long addr = sCz * z + (long)row * N + col;
          if (F32OUT) ((float*)Cout)[addr] = v;
          else        ((bf16*)Cout)[addr] = (bf16)v;
        }
      }
    }
  }
}

// standalone wrapper
template <int BN, int ADDR_MODE, int HAS_BIAS, int DO_SELU, int F32OUT, int SWIZ,
          int AHEAD = 0>
__global__ void __launch_bounds__(256, 2) gemm_bt(
    const bf16* __restrict__ A, const bf16* __restrict__ Bt,
    const float* __restrict__ bias, void* __restrict__ Cout,
    int N, int K, long sAz, long sBz, long sBiasz, long sCz,
    int gx, int gy, int gin) {
  __shared__ __align__(16) bf16 lA[128 * 64];
  __shared__ __align__(16) bf16 lB[BN * 64];
  gemm_bt_body<BN, ADDR_MODE, HAS_BIAS, DO_SELU, F32OUT, SWIZ, AHEAD>(
      blockIdx.x, lA, lB, A, Bt, bias, Cout, N, K, sAz, sBz, sBiasz, sCz, gx, gy, gin);
}

// ---------------- Q/K/V projection GEMM body (id in [0,3072), uniform segments) --------
// All three B-matrices use the permuted row order -> h == ni in the epilogue.
// seg 0 (Q): register-axis head-softmax, writes qs2 (kidx layout, coalesced).
// seg 1 (K): register-axis head-softmax, writes ksT[b,h,d,s] DIRECTLY (transposed,
//            uint2 stores of 4 consecutive s) — the separate softmax/transpose pass
//            is eliminated.
// seg 2 (V): writes vsT[b,h,e,s] directly (same transposed store).
static __device__ __forceinline__ void qkv_body(
    int id, bf16* lA, bf16* lB,
    const bf16* __restrict__ Aq, const bf16* __restrict__ Aenc,
    const bf16* __restrict__ BQ, const bf16* __restrict__ BK,
    const bf16* __restrict__ BV,
    const float* __restrict__ bq, const float* __restrict__ bk,
    const float* __restrict__ bv,
    bf16* __restrict__ qs2, bf16* __restrict__ ksT, bf16* __restrict__ vsT) {
  const int seg = id >> 10, sid = id & 1023;
  const int xcd = sid & 7, r = sid >> 3;
  const int x = r & 15, y = xcd + 8 * (r >> 4);
  const bf16 *A, *Bt; bf16* out; const float* bias;
  if (seg == 0)      { A = Aq;   Bt = BQ; out = qs2; bias = bq; }
  else if (seg == 1) { A = Aenc; Bt = BK; out = ksT; bias = bk; }
  else               { A = Aenc; Bt = BV; out = vsT; bias = bv; }
  const int K = 512;
  const int m0 = y * 128, n0 = x * 128;
  const int t = threadIdx.x;
  const int lane = t & 63, wave = t >> 6;
  const int srow = t >> 3, pch = t & 7, lch = pch ^ (srow & 7);
  const bf16* Ag = A  + (long)(m0 + srow) * K + lch * 8;
  const bf16* Bg = Bt + (long)(n0 + srow) * K + lch * 8;
  bf16* lAp = lA + srow * 64 + pch * 8;
  bf16* lBp = lB + srow * 64 + pch * 8;
  const int wm = (wave >> 1) * 64, wn = (wave & 1) * 64;
  const int fr = lane & 15, fq = lane >> 4;

  f32x4 acc[4][4] = {};
  for (int k0 = 0; k0 < K; k0 += 64) {
    __syncthreads();
#pragma unroll
    for (int i = 0; i < 4; ++i) {
      async16(Ag + k0 + (long)(32 * i) * K, lAp + 32 * i * 64);
      async16(Bg + k0 + (long)(32 * i) * K, lBp + 32 * i * 64);
    }
    __syncthreads();
#pragma unroll
    for (int kk = 0; kk < 2; ++kk) {
      bf16x8 av[4], bfrag[4];
#pragma unroll
      for (int mi = 0; mi < 4; ++mi) {
        int rr = wm + mi * 16 + fr;
        int c = (kk * 4 + fq) ^ (rr & 7);
        av[mi] = *(const bf16x8*)&lA[rr * 64 + c * 8];
      }
#pragma unroll
      for (int ni = 0; ni < 4; ++ni) {
        int rr = wn + ni * 16 + fr;
        int c = (kk * 4 + fq) ^ (rr & 7);
        bfrag[ni] = *(const bf16x8*)&lB[rr * 64 + c * 8];
      }
#pragma unroll
      for (int mi = 0; mi < 4; ++mi)
#pragma unroll
        for (int ni = 0; ni < 4; ++ni)
          acc[mi][ni] = __builtin_amdgcn_mfma_f32_16x16x32_bf16(
              av[mi], bfrag[ni], acc[mi][ni], 0, 0, 0);
    }
  }

  // h == ni; feature index e = fr + 16*((n0+wn)>>6). Bias is bias[ni*512+e].
  const int ebase = fr + 16 * ((n0 + wn) >> 6);
  const float b0 = bias[ebase], b1 = bias[512 + ebase],
              b2 = bias[1024 + ebase], b3 = bias[1536 + ebase];
  if (seg == 0) {
#pragma unroll
    for (int mi = 0; mi < 4; ++mi) {
#pragma unroll
      for (int r = 0; r < 4; ++r) {
        const int row = m0 + wm + mi * 16 + fq * 4 + r;
        float v0 = acc[mi][0][r] + b0;
        float v1 = acc[mi][1][r] + b1;
        float v2 = acc[mi][2][r] + b2;
        float v3 = acc[mi][3][r] + b3;
        float m = fmaxf(fmaxf(v0, v1), fmaxf(v2, v3));
        float p0 = __expf(v0 - m), p1 = __expf(v1 - m),
              p2 = __expf(v2 - m), p3 = __expf(v3 - m);
        float rs = 1.0f / (p0 + p1 + p2 + p3);
        const long ob = (long)row * 2048 + n0 + wn + fr;
        out[ob]      = (bf16)(p0 * rs);
        out[ob + 16] = (bf16)(p1 * rs);
        out[ob + 32] = (bf16)(p2 * rs);
        out[ob + 48] = (bf16)(p3 * rs);
      }
    }
  } else {
    // transposed store: out[((b*4+h)*512+e)*2048 + s], 4 consecutive s per uint2
    const int bb = m0 >> 11;
#pragma unroll
    for (int mi = 0; mi < 4; ++mi) {
      const int s_base = (m0 & 2047) + wm + mi * 16 + fq * 4;
      bf16 tmp[4][4] __attribute__((aligned(8)));   // [ni][r]
#pragma unroll
      for (int r = 0; r < 4; ++r) {
        float v0 = acc[mi][0][r] + b0;
        float v1 = acc[mi][1][r] + b1;
        float v2 = acc[mi][2][r] + b2;
        float v3 = acc[mi][3][r] + b3;
        if (seg == 1) {   // K: head softmax
          float m = fmaxf(fmaxf(v0, v1), fmaxf(v2, v3));
          float p0 = __expf(v0 - m), p1 = __expf(v1 - m),
                p2 = __expf(v2 - m), p3 = __expf(v3 - m);
          float rs = 1.0f / (p0 + p1 + p2 + p3);
          v0 = p0 * rs; v1 = p1 * rs; v2 = p2 * rs; v3 = p3 * rs;
        }
        tmp[0][r] = (bf16)v0; tmp[1][r] = (bf16)v1;
        tmp[2][r] = (bf16)v2; tmp[3][r] = (bf16)v3;
      }
#pragma unroll
      for (int ni = 0; ni < 4; ++ni)
        *(uint2*)(out + ((long)((bb * 4 + ni) * 512 + ebase)) * 2048 + s_base) =
            *(const uint2*)tmp[ni];
    }
  }
}

// ---------------- fused launches ----------------
// [0,2048): K/V projection (writes ksT/vsT transposed) | [2048,2560): Yt DFT GEMM
__global__ void __launch_bounds__(256, 2) fused_kv_yt(
    const bf16* __restrict__ Aenc, const bf16* __restrict__ BK,
    const bf16* __restrict__ BV,
    const float* __restrict__ bk, const float* __restrict__ bv,
    bf16* __restrict__ ksT, bf16* __restrict__ vsT,
    const bf16* __restrict__ Ttrig, const bf16* __restrict__ xdec_b,
    bf16* __restrict__ Yt) {
  __shared__ __align__(16) bf16 smem[16384];   // 32 KiB
  int id = blockIdx.x;
  if (id < 2048)
    qkv_body(id + 1024, smem, smem + 8192, nullptr, Aenc, nullptr, BK, BV,
             nullptr, bk, bv, nullptr, ksT, vsT);
  else
    gemm_bt_body<128, 0, 0, 0, 0, 3, 0>(id - 2048, smem, smem + 8192,
        Ttrig, xdec_b, nullptr, Yt, 2048, 512, 0L, 1048576L, 0L, 2097152L, 16, 8, 32);
}

// [0,512): gc GEMM | [512,1088): CS GEMM
__global__ void __launch_bounds__(256, 2) fused_gc_cs(
    const bf16* __restrict__ ksT, const bf16* __restrict__ vsT,
    bf16* __restrict__ gc,
    const bf16* __restrict__ Atrig2, const bf16* __restrict__ Yf2,
    bf16* __restrict__ CSb) {
  __shared__ __align__(16) bf16 smem[12288];   // 24 KiB
  int id = blockIdx.x;
  if (id < 512)
    gemm_bt_body<64, 0, 0, 0, 0, 2, 0>(id, smem, smem + 8192,
        ksT, vsT, nullptr, gc, 512, 2048, 1048576L, 1048576L, 0L, 262144L, 8, 4, 32);
  else
    gemm_bt_body<64, 0, 0, 0, 0, 2, 2>(id - 512, smem, smem + 8192,
        Atrig2, Yf2, nullptr, CSb, 512, 1088, 1253376L, 557056L, 0L, 589824L, 8, 9, 72);
}

// [0,1024): Q projection + head-softmax | [1024,1536): gwT GEMM (kidx layout)
__global__ void __launch_bounds__(256, 2) fused_q_gw(
    const bf16* __restrict__ Aq, const bf16* __restrict__ BQ,
    const float* __restrict__ bq, bf16* __restrict__ qs2,
    const bf16* __restrict__ WoTh, const bf16* __restrict__ gc,
    bf16* __restrict__ gwT) {
  __shared__ __align__(16) bf16 smem[16384];   // 32 KiB
  int id = blockIdx.x;
  if (id < 1024)
    qkv_body(id, smem, smem + 8192, Aq, nullptr, BQ, nullptr, nullptr,
             bq, nullptr, nullptr, qs2, nullptr, nullptr);
  else
    gemm_bt_body<64, 9, 0, 0, 0, 2, 1>(id - 1024, smem, smem + 8192,
        WoTh, gc, nullptr, gwT, 512, 512, 262144L, 262144L, 0L, 0L, 8, 4, 32);
}

// ---------------- launcher ----------------
extern "C" void kernel_launch(void* const* d_in, const int* in_sizes, int n_in,
                              void* d_out, int out_size, void* d_ws, size_t ws_size,
                              hipStream_t stream) {
  (void)in_sizes; (void)n_in; (void)out_size; (void)ws_size;
  const float* x_enc = (const float*)d_in[0];
  const float* x_dec = (const float*)d_in[1];
  const float* Wq = (const float*)d_in[2];
  const float* bq = (const float*)d_in[3];
  const float* Wk = (const float*)d_in[4];
  const float* bk = (const float*)d_in[5];
  const float* Wv = (const float*)d_in[6];
  const float* bv = (const float*)d_in[7];
  const float* Wo = (const float*)d_in[8];
  const float* bo = (const float*)d_in[9];
  const float* g1 = (const float*)d_in[10];
  const float* be1 = (const float*)d_in[11];
  const float* g2 = (const float*)d_in[12];
  const float* be2 = (const float*)d_in[13];
  const float* W1 = (const float*)d_in[14];
  const float* b1 = (const float*)d_in[15];
  const float* W2 = (const float*)d_in[16];
  const float* b2 = (const float*)d_in[17];
  const float* g3 = (const float*)d_in[18];
  const float* be3 = (const float*)d_in[19];

  char* ws = (char*)d_ws;
  const size_t MB = 1u << 20;
  // time-disjoint aliasing, peak 255 MiB. Launch order:
  // L1 prep | L2 kv+yt | L3 fold | L4 gc+cs | L5 ln1 | L6 q+gw | L7 attn
  // L8 ln2 | L9 w1 | L10 w2 | L11 ln3
  bf16*  BtQ    = (bf16*) (ws + 0);        // [0,2)   W:L1 R:L6
  bf16*  midb   = (bf16*) (ws + 0);        // [0,32)  W:L9 R:L10
  bf16*  ksT    = (bf16*) (ws + 32 * MB);  // [32,64) W:L2 R:L4
  bf16*  attn_b = (bf16*) (ws + 32 * MB);  // [32,64) W:L7 R:L8
  bf16*  vsT    = (bf16*) (ws + 64 * MB);  // [64,96) W:L2 R:L4
  bf16*  ff_b   = (bf16*) (ws + 72 * MB);  // [72,96) W:L10 R:L11
  bf16*  Atrig2 = (bf16*) (ws + 96 * MB);  // [96,101) W:L1 R:L4
  bf16*  Ttrig  = (bf16*) (ws + 101 * MB); // [101,102) W:L1 R:L2
  bf16*  CSb    = (bf16*) (ws + 102 * MB); // [102,112) W:L4 R:L5
  bf16*  qs2    = (bf16*) (ws + 96 * MB);  // [96,128) W:L6 R:L7
  bf16*  xenc_b = (bf16*) (ws + 128 * MB); // [128,136) W:L1 R:L2
  bf16*  BtK    = (bf16*) (ws + 136 * MB); // [136,138) W:L1 R:L2
  bf16*  BtV    = (bf16*) (ws + 138 * MB); // [138,140) W:L1 R:L2
  bf16*  xd_b   = (bf16*) (ws + 192 * MB); // [192,200) W:L5 R:L6,L8
  bf16*  x2_b   = (bf16*) (ws + 200 * MB); // [200,208) W:L8 R:L9,L11
  bf16*  gwT    = (bf16*) (ws + 208 * MB); // [208,216) W:L6 R:L7
  bf16*  Yt     = (bf16*) (ws + 216 * MB); // [216,232) W:L2 R:L3
  bf16*  gc     = (bf16*) (ws + 216 * MB); // [216,224) W:L4 R:L6 (Yt dead after L3)
  bf16*  Yf2    = (bf16*) (ws + 232 * MB); // [232,241) W:L3 R:L4
  bf16*  WoTh   = (bf16*) (ws + 241 * MB); // [241,243) W:L1 R:L6
  bf16*  W1T    = (bf16*) (ws + 243 * MB); // W:L1 R:L9
  bf16*  W2T    = (bf16*) (ws + 245 * MB); // W:L1 R:L10
  bf16*  xdec_b = (bf16*) (ws + 247 * MB); // [247,255) W:L1 R:L2

  // --- L1: prep ---
  prep_all<<<50752, 256, 0, stream>>>(x_dec, x_enc, Ttrig, Atrig2, xdec_b, xenc_b,
                                      Wq, Wk, Wv, Wo, W1, W2,
                                      BtQ, BtK, BtV, WoTh, W1T, W2T);

  // --- L2: K/V projection (direct transposed+softmaxed stores)  ∥  Yt DFT GEMM ---
  fused_kv_yt<<<2560, 256, 0, stream>>>(xenc_b, BtK, BtV, bk, bv, ksT, vsT,
                                        Ttrig, xdec_b, Yt);

  // --- L3: fold ---
  fold_y<<<17408, 256, 0, stream>>>(Yt, Yf2);

  // --- L4: gc GEMM  ∥  CS GEMM ---
  fused_gc_cs<<<1088, 256, 0, stream>>>(ksT, vsT, gc, Atrig2, Yf2, CSb);

  // --- L5: LN1 ---
  ln1_kernel<<<8192, 256, 0, stream>>>(x_dec, CSb, g1, be1, xd_b);

  // --- L6: Q projection+softmax  ∥  gwT ---
  fused_q_gw<<<1536, 256, 0, stream>>>(xd_b, BtQ, bq, qs2, WoTh, gc, gwT);

  // --- L7: attn = qs2 . gwT^T + bo ---
  gemm_bt<64, 0, 1, 0, 0, 1><<<512, 256, 0, stream>>>(
      qs2, gwT, bo, attn_b, 512, 2048, 4194304L, 1048576L, 0L, 1048576L, 8, 16, 32);
  // --- L8: LN2 ---
  ln_kernel<bf16, bf16, 1, 0><<<8192, 256, 0, stream>>>(
      xd_b, attn_b, g2, be2, x2_b, nullptr);

  // --- L9: FFN W1 + SELU ---
  gemm_bt<128, 0, 1, 1, 0, 1><<<1024, 256, 0, stream>>>(
      x2_b, W1T, b1, midb, 2048, 512, 0L, 0L, 0L, 0L, 16, 64, 16);
  // --- L10: FFN W2 ---
  gemm_bt<64, 0, 1, 0, 0, 1><<<512, 256, 0, stream>>>(
      midb, W2T, b2, ff_b, 512, 2048, 0L, 0L, 0L, 0L, 8, 64, 8);
  // --- L11: LN3 -> output (f32) ---
  ln_kernel<bf16, bf16, 0, 1><<<8192, 256, 0, stream>>>(
      x2_b, ff_b, g3, be3, nullptr, (float*)d_out);
}

// Round 11
// 378.968 us; speedup vs baseline: 1.0838x; 1.0078x over previous
//
#include <hip/hip_runtime.h>
#include <stdint.h>

typedef __bf16 bf16;
typedef __bf16 bf16x8 __attribute__((ext_vector_type(8)));
typedef float f32x4 __attribute__((ext_vector_type(4)));

// ---------------- async global->LDS (16B per lane) ----------------
static __device__ __forceinline__ void async16(const void* g, void* l) {
  __builtin_amdgcn_global_load_lds(
      (__attribute__((address_space(1))) void*)g,
      (__attribute__((address_space(3))) void*)l, 16, 0, 0);
}

// ---------------- merged prep ----------------
// blocks [0,2048) Ttrig | [2048,11840) Atrig2 (cos|sin half-DFT, K=1088) |
// [11840,28224) cast x_dec | [28224,44608) cast x_enc | [44608,50752) weight transposes
// BtQ/BtK/BtV ALL use the h-in-bits-4:5 permuted row order n=(e&15)|(h<<4)|((e>>4)<<6)
// so the QKV epilogue gets h==ni: register-axis softmax (Q,K) and register-local
// transposed stores (K,V) — the separate K/V softmax/transpose pass is eliminated.
__global__ void __launch_bounds__(256) prep_all(
    const float* __restrict__ xdec, const float* __restrict__ xenc,
    bf16* __restrict__ Ttrig, bf16* __restrict__ Atrig2,
    bf16* __restrict__ xdec_b, bf16* __restrict__ xenc_b,
    const float* __restrict__ Wq, const float* __restrict__ Wk,
    const float* __restrict__ Wv, const float* __restrict__ Wo,
    const float* __restrict__ W1, const float* __restrict__ W2,
    bf16* __restrict__ BtQ, bf16* __restrict__ BtK, bf16* __restrict__ BtV,
    bf16* __restrict__ WoTh, bf16* __restrict__ W1T, bf16* __restrict__ W2T) {
  __shared__ bf16 tile[32][33];
  int id = blockIdx.x;
  if (id < 2048) {                     // Ttrig[1024][512]
    int idx = id * 256 + threadIdx.x;
    int d = idx & 511, jp = idx >> 9;
    int jj = jp >> 1, p = jp & 1;
    int t = (d * jj) & 511;
    float ang = (float)t * (6.283185307179586f / 512.0f);
    Ttrig[idx] = (bf16)(p ? __sinf(ang) : __cosf(ang));
  } else if (id < 11840) {             // Atrig2[2][1152][1088]: half 0 cos, half 1 -sin
    int idx = (id - 2048) * 256 + threadIdx.x;   // < 2506752
    int k = idx % 1088;
    int rr = idx / 1088;
    int r = rr % 1152, half = rr / 1152;
    float v = 0.0f;
    int tt = (r * k) & 2047;
    float ang = (float)tt * (6.283185307179586f / 2048.0f);
    if (half == 0) { if (r <= 1024 && k <= 1024) v = __cosf(ang); }
    else           { if (r <= 1023 && k >= 1 && k <= 1023) v = -__sinf(ang); }
    Atrig2[idx] = (bf16)v;
  } else if (id < 28224) {
    int i = (id - 11840) * 256 + threadIdx.x;
    xdec_b[i] = (bf16)xdec[i];
  } else if (id < 44608) {
    int i = (id - 28224) * 256 + threadIdx.x;
    xenc_b[i] = (bf16)xenc[i];
  } else {
    int id2 = id - 44608;
    int kind = id2 >> 10, t = id2 & 1023;
    const float* in; bf16* out; int R, C, rt, ct;
    bool iperm = false, hsel = false; int hh = 0;
    if (kind == 0)      { in = Wq; out = BtQ; R = 2048; C = 512; rt = t >> 4; ct = t & 15; iperm = true; }
    else if (kind == 1) { in = Wk; out = BtK; R = 2048; C = 512; rt = t >> 4; ct = t & 15; iperm = true; }
    else if (kind == 2) { in = Wv; out = BtV; R = 2048; C = 512; rt = t >> 4; ct = t & 15; iperm = true; }
    else if (kind == 3) {              // WoTh[h][n][e] = Wo[4e+h][n]
      int zz = t >> 8, tt = t & 255;
      in = Wo; out = WoTh + (long)zz * 262144;
      R = 512; C = 512; rt = tt >> 4; ct = tt & 15; hsel = true; hh = zz;
    }
    else if (kind == 4) { in = W1; out = W1T; R = 512; C = 2048; rt = t >> 6; ct = t & 63; }
    else                { in = W2; out = W2T; R = 2048; C = 512; rt = t >> 4; ct = t & 15; }
    int c0 = ct * 32, r0 = rt * 32;
    int tx = threadIdx.x & 31, ty = threadIdx.x >> 5;
#pragma unroll
    for (int i = 0; i < 32; i += 8) {
      int r = r0 + ty + i;
      int rr = hsel ? (4 * r + hh) : r;
      tile[ty + i][tx] = (bf16)in[(long)rr * C + (c0 + tx)];
    }
    __syncthreads();
#pragma unroll
    for (int i = 0; i < 32; i += 8) {
      int cc = c0 + ty + i, rr = r0 + tx;
      if (iperm) {  // Bt row from W row h*512+din; cc = e, rr>>9 = h, rr&511 = din
        int e = cc, h = rr >> 9;
        int n = (e & 15) | (h << 4) | ((e >> 4) << 6);
        out[((long)n << 9) + (rr & 511)] = tile[tx][ty + i];
      } else {
        out[(long)cc * R + rr] = tile[tx][ty + i];
      }
    }
  }
}

// Fold Yt [4][512][4096] -> Yf2 [8][512][1088]: z<4 cos-fold Ycf[b], z>=4 sin-fold Ysf[b]
__global__ void __launch_bounds__(256) fold_y(const bf16* __restrict__ Yt,
                                              bf16* __restrict__ Yf2) {
  int idx = blockIdx.x * 256 + threadIdx.x;   // 8*512*1088 = 4456448
  int k = idx % 1088;
  int rr = idx / 1088;
  int j = rr & 511, z = rr >> 9;
  int b = z & 3, half = z >> 2;
  const bf16* yin = Yt + (long)b * 2097152 + (long)j * 4096;
  float v = 0.0f;
  if (half == 0) {
    if (k == 0) v = (float)yin[0];
    else if (k == 1024) v = (float)yin[1024];
    else if (k < 1024) v = (float)yin[k] + (float)yin[2048 - k];
  } else {
    if (k >= 1 && k <= 1023) v = (float)yin[2048 + k] - (float)yin[4096 - k];
  }
  Yf2[(long)z * 557056 + (long)j * 1088 + k] = (bf16)v;
}

// ---------------- LN1 with DFT recombination: xf[s] = C[s'] ± S[s'] ----------------
__global__ void __launch_bounds__(256) ln1_kernel(
    const float* __restrict__ xdec, const bf16* __restrict__ CSb,
    const float* __restrict__ g, const float* __restrict__ be,
    bf16* __restrict__ outb) {
  const int row = blockIdx.x, t = threadIdx.x;
  const int b = row >> 11, s = row & 2047;
  const int sp = (s <= 1024) ? s : 2048 - s;
  const float sgn = (s <= 1024) ? 1.0f : -1.0f;
  const bf16* Crow = CSb + ((long)b * 1152 + sp) * 512;
  const bf16* Srow = CSb + ((long)(b + 4) * 1152 + sp) * 512;
  const long base = (long)row * 512;
  float v0 = xdec[base + t] + (float)Crow[t] + sgn * (float)Srow[t];
  float v1 = xdec[base + t + 256] + (float)Crow[t + 256] + sgn * (float)Srow[t + 256];
  float sm = v0 + v1, q = v0 * v0 + v1 * v1;
#pragma unroll
  for (int off = 32; off > 0; off >>= 1) {
    sm += __shfl_down(sm, off);
    q += __shfl_down(q, off);
  }
  __shared__ float red[8];
  const int wv = t >> 6, ln = t & 63;
  if (ln == 0) { red[wv] = sm; red[wv + 4] = q; }
  __syncthreads();
  float S = red[0] + red[1] + red[2] + red[3];
  float Q = red[4] + red[5] + red[6] + red[7];
  float mu = S * (1.0f / 512.0f);
  float var = Q * (1.0f / 512.0f) - mu * mu;
  float rstd = rsqrtf(var + 1e-5f);
  outb[base + t] = (bf16)(g[t] * (v0 - mu) * rstd + be[t]);
  outb[base + t + 256] = (bf16)(g[t + 256] * (v1 - mu) * rstd + be[t + 256]);
}

// ---------------- generic LayerNorm ----------------
template <typename TA, typename TB, int WRITE_BF16, int WRITE_F32>
__global__ void __launch_bounds__(256) ln_kernel(
    const TA* __restrict__ A, const TB* __restrict__ Bv,
    const float* __restrict__ g, const float* __restrict__ be,
    bf16* __restrict__ outb, float* __restrict__ outf) {
  const int row = blockIdx.x, t = threadIdx.x;
  const long base = (long)row * 512;
  float v0 = (float)A[base + t] + (float)Bv[base + t];
  float v1 = (float)A[base + t + 256] + (float)Bv[base + t + 256];
  float s = v0 + v1, q = v0 * v0 + v1 * v1;
#pragma unroll
  for (int off = 32; off > 0; off >>= 1) {
    s += __shfl_down(s, off);
    q += __shfl_down(q, off);
  }
  __shared__ float red[8];
  const int wv = t >> 6, ln = t & 63;
  if (ln == 0) { red[wv] = s; red[wv + 4] = q; }
  __syncthreads();
  float S = red[0] + red[1] + red[2] + red[3];
  float Q = red[4] + red[5] + red[6] + red[7];
  float mu = S * (1.0f / 512.0f);
  float var = Q * (1.0f / 512.0f) - mu * mu;
  float rstd = rsqrtf(var + 1e-5f);
  float o0 = g[t] * (v0 - mu) * rstd + be[t];
  float o1 = g[t + 256] * (v1 - mu) * rstd + be[t + 256];
  if (WRITE_BF16) { outb[base + t] = (bf16)o0; outb[base + t + 256] = (bf16)o1; }
  if (WRITE_F32)  { outf[base + t] = o0; outf[base + t + 256] = o1; }
}

// ---------------- GEMM body: C = A[M,K] * Bt[N,K]^T (single-buffer m97 K-loop) ---------
// SWIZ: 0 plain; 1 group-by-y; 2 group-by-z; 3 group-by-x. gin = blocks per group.
// ADDR_MODE: 0 plain (sCz*z); 9 gw out (col&15)|(h<<4)|((col>>4)<<6).
// HAS_BIAS: 0 none, 1 bias[sBiasz*z+col].
// AHEAD: 0 A+=sAz*z; 1 A+=sAz*(z&3); 2 A+=sAz*(z>>2).
template <int BN, int ADDR_MODE, int HAS_BIAS, int DO_SELU, int F32OUT, int SWIZ,
          int AHEAD>
static __device__ __forceinline__ void gemm_bt_body(
    int id, bf16* lA, bf16* lB,
    const bf16* __restrict__ A, const bf16* __restrict__ Bt,
    const float* __restrict__ bias, void* __restrict__ Cout,
    int N, int K, long sAz, long sBz, long sBiasz, long sCz,
    int gx, int gy, int gin) {
  int x, y, z;
  {
    if (SWIZ == 0) {
      x = id % gx; int t2 = id / gx; y = t2 % gy; z = t2 / gy;
    } else {
      int xcd = id & 7, r = id >> 3;
      int inner = r % gin, G = xcd + 8 * (r / gin);
      if (SWIZ == 1)      { y = G; x = inner % gx; z = inner / gx; }
      else if (SWIZ == 2) { z = G; x = inner % gx; y = inner / gx; }
      else                { x = G; y = inner % gy; z = inner / gy; }
    }
  }
  A  += (AHEAD == 1) ? sAz * (z & 3) : (AHEAD == 2) ? sAz * (z >> 2) : sAz * z;
  Bt += sBz * z;
  const int m0 = y * 128, n0 = x * BN;
  const int t = threadIdx.x;
  const int lane = t & 63, wave = t >> 6;
  const int srow = t >> 3;
  const int pch  = t & 7;
  const int lch  = pch ^ (srow & 7);   // XOR bank swizzle (global-side)
  const bf16* Ag = A  + (long)(m0 + srow) * K + lch * 8;
  const bf16* Bg = Bt + (long)(n0 + srow) * K + lch * 8;
  bf16* lAp = lA + srow * 64 + pch * 8;
  bf16* lBp = lB + srow * 64 + pch * 8;
  constexpr int MI = (BN == 128) ? 4 : 2;
  const int wm = (BN == 128) ? (wave >> 1) * 64 : wave * 32;
  const int wn = (BN == 128) ? (wave & 1) * 64 : 0;
  const int fr = lane & 15, fq = lane >> 4;

  f32x4 acc[MI][4] = {};

  for (int k0 = 0; k0 < K; k0 += 64) {
    __syncthreads();
#pragma unroll
    for (int i = 0; i < 4; ++i)
      async16(Ag + k0 + (long)(32 * i) * K, lAp + 32 * i * 64);
#pragma unroll
    for (int i = 0; i < BN / 32; ++i)
      async16(Bg + k0 + (long)(32 * i) * K, lBp + 32 * i * 64);
    __syncthreads();
#pragma unroll
    for (int kk = 0; kk < 2; ++kk) {
      bf16x8 av[MI], bfrag[4];
#pragma unroll
      for (int mi = 0; mi < MI; ++mi) {
        int r = wm + mi * 16 + fr;
        int c = (kk * 4 + fq) ^ (r & 7);
        av[mi] = *(const bf16x8*)&lA[r * 64 + c * 8];
      }
#pragma unroll
      for (int ni = 0; ni < 4; ++ni) {
        int r = wn + ni * 16 + fr;
        int c = (kk * 4 + fq) ^ (r & 7);
        bfrag[ni] = *(const bf16x8*)&lB[r * 64 + c * 8];
      }
#pragma unroll
      for (int mi = 0; mi < MI; ++mi)
#pragma unroll
        for (int ni = 0; ni < 4; ++ni)
          acc[mi][ni] = __builtin_amdgcn_mfma_f32_16x16x32_bf16(
              av[mi], bfrag[ni], acc[mi][ni], 0, 0, 0);
    }
  }

  // epilogue: C/D layout col = lane&15, row = (lane>>4)*4 + reg
#pragma unroll
  for (int mi = 0; mi < MI; ++mi) {
#pragma unroll
    for (int ni = 0; ni < 4; ++ni) {
      const int col = n0 + wn + ni * 16 + fr;
      float bias_v = 0.0f;
      if (HAS_BIAS == 1) bias_v = bias[sBiasz * z + col];
      if (ADDR_MODE == 9) {                  // z=b*4+h -> Bt_b[row][(col&15)|(h<<4)|((col>>4)<<6)]
        const int b = z >> 2, h = z & 3;
        const int kidx = (col & 15) | (h << 4) | ((col >> 4) << 6);
#pragma unroll
        for (int r = 0; r < 4; ++r) {
          const int row = m0 + wm + mi * 16 + fq * 4 + r;
          ((bf16*)Cout)[((long)(b * 512 + row)) * 2048 + kidx] =
              (bf16)(acc[mi][ni][r] + bias_v);
        }
      } else {
#pragma unroll
        for (int r = 0; r < 4; ++r) {
          const int row = m0 + wm + mi * 16 + fq * 4 + r;
          float v = acc[mi][ni][r] + bias_v;
          if (DO_SELU) v = v > 0.0f ? 1.0507009873554805f * v
                                    : 1.7580993408473766f * (__expf(v) - 1.0f);
          long addr = sCz * z + (long)row * N + col;
          if (F32OUT) ((float*)Cout)[addr] = v;
          else        ((bf16*)Cout)[addr] = (bf16)v;
        }
      }
    }
  }
}

// standalone wrapper
template <int BN, int ADDR_MODE, int HAS_BIAS, int DO_SELU, int F32OUT, int SWIZ,
          int AHEAD = 0>
__global__ void __launch_bounds__(256, 2) gemm_bt(
    const bf16* __restrict__ A, const bf16* __restrict__ Bt,
    const float* __restrict__ bias, void* __restrict__ Cout,
    int N, int K, long sAz, long sBz, long sBiasz, long sCz,
    int gx, int gy, int gin) {
  __shared__ __align__(16) bf16 lA[128 * 64];
  __shared__ __align__(16) bf16 lB[BN * 64];
  gemm_bt_body<BN, ADDR_MODE, HAS_BIAS, DO_SELU, F32OUT, SWIZ, AHEAD>(
      blockIdx.x, lA, lB, A, Bt, bias, Cout, N, K, sAz, sBz, sBiasz, sCz, gx, gy, gin);
}

// ---------------- Q/K/V projection GEMM body (id in [0,3072), uniform segments) --------
// All three B-matrices use the permuted row order -> h == ni in the epilogue.
// seg 0 (Q): register-axis head-softmax, writes qs2 (kidx layout, coalesced).
// seg 1 (K): register-axis head-softmax, transposed store via LDS -> 256B-coalesced.
// seg 2 (V): transposed store via LDS (no softmax).
// NOTE: lA must point at a contiguous 32 KiB (lB = lA+8192); segs 1/2 reuse it as the
// 128x128 transpose buffer after the K-loop.
static __device__ __forceinline__ void qkv_body(
    int id, bf16* lA, bf16* lB,
    const bf16* __restrict__ Aq, const bf16* __restrict__ Aenc,
    const bf16* __restrict__ BQ, const bf16* __restrict__ BK,
    const bf16* __restrict__ BV,
    const float* __restrict__ bq, const float* __restrict__ bk,
    const float* __restrict__ bv,
    bf16* __restrict__ qs2, bf16* __restrict__ ksT, bf16* __restrict__ vsT) {
  const int seg = id >> 10, sid = id & 1023;
  const int xcd = sid & 7, r = sid >> 3;
  const int x = r & 15, y = xcd + 8 * (r >> 4);
  const bf16 *A, *Bt; bf16* out; const float* bias;
  if (seg == 0)      { A = Aq;   Bt = BQ; out = qs2; bias = bq; }
  else if (seg == 1) { A = Aenc; Bt = BK; out = ksT; bias = bk; }
  else               { A = Aenc; Bt = BV; out = vsT; bias = bv; }
  const int K = 512;
  const int m0 = y * 128, n0 = x * 128;
  const int t = threadIdx.x;
  const int lane = t & 63, wave = t >> 6;
  const int srow = t >> 3, pch = t & 7, lch = pch ^ (srow & 7);
  const bf16* Ag = A  + (long)(m0 + srow) * K + lch * 8;
  const bf16* Bg = Bt + (long)(n0 + srow) * K + lch * 8;
  bf16* lAp = lA + srow * 64 + pch * 8;
  bf16* lBp = lB + srow * 64 + pch * 8;
  const int wm = (wave >> 1) * 64, wn = (wave & 1) * 64;
  const int fr = lane & 15, fq = lane >> 4;

  f32x4 acc[4][4] = {};
  for (int k0 = 0; k0 < K; k0 += 64) {
    __syncthreads();
#pragma unroll
    for (int i = 0; i < 4; ++i) {
      async16(Ag + k0 + (long)(32 * i) * K, lAp + 32 * i * 64);
      async16(Bg + k0 + (long)(32 * i) * K, lBp + 32 * i * 64);
    }
    __syncthreads();
#pragma unroll
    for (int kk = 0; kk < 2; ++kk) {
      bf16x8 av[4], bfrag[4];
#pragma unroll
      for (int mi = 0; mi < 4; ++mi) {
        int rr = wm + mi * 16 + fr;
        int c = (kk * 4 + fq) ^ (rr & 7);
        av[mi] = *(const bf16x8*)&lA[rr * 64 + c * 8];
      }
#pragma unroll
      for (int ni = 0; ni < 4; ++ni) {
        int rr = wn + ni * 16 + fr;
        int c = (kk * 4 + fq) ^ (rr & 7);
        bfrag[ni] = *(const bf16x8*)&lB[rr * 64 + c * 8];
      }
#pragma unroll
      for (int mi = 0; mi < 4; ++mi)
#pragma unroll
        for (int ni = 0; ni < 4; ++ni)
          acc[mi][ni] = __builtin_amdgcn_mfma_f32_16x16x32_bf16(
              av[mi], bfrag[ni], acc[mi][ni], 0, 0, 0);
    }
  }

  // h == ni; feature index e = fr + 16*((n0+wn)>>6). Bias is bias[ni*512+e].
  const int ebase = fr + 16 * ((n0 + wn) >> 6);
  const float b0 = bias[ebase], b1 = bias[512 + ebase],
              b2 = bias[1024 + ebase], b3 = bias[1536 + ebase];
  if (seg == 0) {
#pragma unroll
    for (int mi = 0; mi < 4; ++mi) {
#pragma unroll
      for (int r = 0; r < 4; ++r) {
        const int row = m0 + wm + mi * 16 + fq * 4 + r;
        float v0 = acc[mi][0][r] + b0;
        float v1 = acc[mi][1][r] + b1;
        float v2 = acc[mi][2][r] + b2;
        float v3 = acc[mi][3][r] + b3;
        float m = fmaxf(fmaxf(v0, v1), fmaxf(v2, v3));
        float p0 = __expf(v0 - m), p1 = __expf(v1 - m),
              p2 = __expf(v2 - m), p3 = __expf(v3 - m);
        float rs = 1.0f / (p0 + p1 + p2 + p3);
        const long ob = (long)row * 2048 + n0 + wn + fr;
        out[ob]      = (bf16)(p0 * rs);
        out[ob + 16] = (bf16)(p1 * rs);
        out[ob + 32] = (bf16)(p2 * rs);
        out[ob + 48] = (bf16)(p3 * rs);
      }
    }
  } else {
    // Transposed store via LDS: block tile = rows (h*32+e_loc) in [0,128) x s in [0,128).
    // XOR-swizzle 16B chunks by (row&15): write uint2 (aligned-4 within one 8-chunk),
    // read uint4 -> 256B-contiguous global stores. <=2-way LDS conflicts (free, m136).
    bf16* lT = lA;                         // lA/lB contiguous 32 KiB = 128x128 bf16
    const int bb = m0 >> 11;
    const int s_tile = m0 & 2047;
    const int e_loc = fr + 16 * (wn >> 6); // [0,32)
    __syncthreads();                       // all waves done with lA/lB ds_reads
#pragma unroll
    for (int mi = 0; mi < 4; ++mi) {
      const int s0 = wm + mi * 16 + fq * 4;   // [0,128), multiple of 4
      bf16 tmp[4][4] __attribute__((aligned(8)));   // [h][r]
#pragma unroll
      for (int r = 0; r < 4; ++r) {
        float v0 = acc[mi][0][r] + b0;
        float v1 = acc[mi][1][r] + b1;
        float v2 = acc[mi][2][r] + b2;
        float v3 = acc[mi][3][r] + b3;
        if (seg == 1) {   // K: head softmax
          float m = fmaxf(fmaxf(v0, v1), fmaxf(v2, v3));
          float p0 = __expf(v0 - m), p1 = __expf(v1 - m),
                p2 = __expf(v2 - m), p3 = __expf(v3 - m);
          float rs = 1.0f / (p0 + p1 + p2 + p3);
          v0 = p0 * rs; v1 = p1 * rs; v2 = p2 * rs; v3 = p3 * rs;
        }
        tmp[0][r] = (bf16)v0; tmp[1][r] = (bf16)v1;
        tmp[2][r] = (bf16)v2; tmp[3][r] = (bf16)v3;
      }
#pragma unroll
      for (int ni = 0; ni < 4; ++ni) {
        const int row = ni * 32 + e_loc;   // [0,128)
        const int el = row * 128 + ((((s0 >> 3) ^ (row & 15)) << 3) | (s0 & 7));
        *(uint2*)&lT[el] = *(const uint2*)tmp[ni];
      }
    }
    __syncthreads();
    const int c = lane & 15, rg = lane >> 4;   // chunk idx, row-group
#pragma unroll
    for (int i = 0; i < 8; ++i) {
      const int row = wave * 32 + rg + i * 4;  // [0,128)
      const int el = row * 128 + ((c ^ (row & 15)) << 3);
      uint4 v = *(const uint4*)&lT[el];
      const int h = row >> 5, e = (row & 31) + 32 * x;
      *(uint4*)(out + ((long)((bb * 4 + h) * 512 + e)) * 2048 + s_tile + c * 8) = v;
    }
  }
}

// ---------------- fused launches ----------------
// [0,2048): K/V projection (writes ksT/vsT transposed) | [2048,2560): Yt DFT GEMM
__global__ void __launch_bounds__(256, 2) fused_kv_yt(
    const bf16* __restrict__ Aenc, const bf16* __restrict__ BK,
    const bf16* __restrict__ BV,
    const float* __restrict__ bk, const float* __restrict__ bv,
    bf16* __restrict__ ksT, bf16* __restrict__ vsT,
    const bf16* __restrict__ Ttrig, const bf16* __restrict__ xdec_b,
    bf16* __restrict__ Yt) {
  __shared__ __align__(16) bf16 smem[16384];   // 32 KiB
  int id = blockIdx.x;
  if (id < 2048)
    qkv_body(id + 1024, smem, smem + 8192, nullptr, Aenc, nullptr, BK, BV,
             nullptr, bk, bv, nullptr, ksT, vsT);
  else
    gemm_bt_body<128, 0, 0, 0, 0, 3, 0>(id - 2048, smem, smem + 8192,
        Ttrig, xdec_b, nullptr, Yt, 2048, 512, 0L, 1048576L, 0L, 2097152L, 16, 8, 32);
}

// [0,512): gc GEMM | [512,1088): CS GEMM
__global__ void __launch_bounds__(256, 2) fused_gc_cs(
    const bf16* __restrict__ ksT, const bf16* __restrict__ vsT,
    bf16* __restrict__ gc,
    const bf16* __restrict__ Atrig2, const bf16* __restrict__ Yf2,
    bf16* __restrict__ CSb) {
  __shared__ __align__(16) bf16 smem[12288];   // 24 KiB
  int id = blockIdx.x;
  if (id < 512)
    gemm_bt_body<64, 0, 0, 0, 0, 2, 0>(id, smem, smem + 8192,
        ksT, vsT, nullptr, gc, 512, 2048, 1048576L, 1048576L, 0L, 262144L, 8, 4, 32);
  else
    gemm_bt_body<64, 0, 0, 0, 0, 2, 2>(id - 512, smem, smem + 8192,
        Atrig2, Yf2, nullptr, CSb, 512, 1088, 1253376L, 557056L, 0L, 589824L, 8, 9, 72);
}

// [0,1024): Q projection + head-softmax | [1024,1536): gwT GEMM (kidx layout)
__global__ void __launch_bounds__(256, 2) fused_q_gw(
    const bf16* __restrict__ Aq, const bf16* __restrict__ BQ,
    const float* __restrict__ bq, bf16* __restrict__ qs2,
    const bf16* __restrict__ WoTh, const bf16* __restrict__ gc,
    bf16* __restrict__ gwT) {
  __shared__ __align__(16) bf16 smem[16384];   // 32 KiB
  int id = blockIdx.x;
  if (id < 1024)
    qkv_body(id, smem, smem + 8192, Aq, nullptr, BQ, nullptr, nullptr,
             bq, nullptr, nullptr, qs2, nullptr, nullptr);
  else
    gemm_bt_body<64, 9, 0, 0, 0, 2, 1>(id - 1024, smem, smem + 8192,
        WoTh, gc, nullptr, gwT, 512, 512, 262144L, 262144L, 0L, 0L, 8, 4, 32);
}

// ---------------- launcher ----------------
extern "C" void kernel_launch(void* const* d_in, const int* in_sizes, int n_in,
                              void* d_out, int out_size, void* d_ws, size_t ws_size,
                              hipStream_t stream) {
  (void)in_sizes; (void)n_in; (void)out_size; (void)ws_size;
  const float* x_enc = (const float*)d_in[0];
  const float* x_dec = (const float*)d_in[1];
  const float* Wq = (const float*)d_in[2];
  const float* bq = (const float*)d_in[3];
  const float* Wk = (const float*)d_in[4];
  const float* bk = (const float*)d_in[5];
  const float* Wv = (const float*)d_in[6];
  const float* bv = (const float*)d_in[7];
  const float* Wo = (const float*)d_in[8];
  const float* bo = (const float*)d_in[9];
  const float* g1 = (const float*)d_in[10];
  const float* be1 = (const float*)d_in[11];
  const float* g2 = (const float*)d_in[12];
  const float* be2 = (const float*)d_in[13];
  const float* W1 = (const float*)d_in[14];
  const float* b1 = (const float*)d_in[15];
  const float* W2 = (const float*)d_in[16];
  const float* b2 = (const float*)d_in[17];
  const float* g3 = (const float*)d_in[18];
  const float* be3 = (const float*)d_in[19];

  char* ws = (char*)d_ws;
  const size_t MB = 1u << 20;
  // time-disjoint aliasing, peak 255 MiB. Launch order:
  // L1 prep | L2 kv+yt | L3 fold | L4 gc+cs | L5 ln1 | L6 q+gw | L7 attn
  // L8 ln2 | L9 w1 | L10 w2 | L11 ln3
  bf16*  BtQ    = (bf16*) (ws + 0);        // [0,2)   W:L1 R:L6
  bf16*  midb   = (bf16*) (ws + 0);        // [0,32)  W:L9 R:L10
  bf16*  ksT    = (bf16*) (ws + 32 * MB);  // [32,64) W:L2 R:L4
  bf16*  attn_b = (bf16*) (ws + 32 * MB);  // [32,64) W:L7 R:L8
  bf16*  vsT    = (bf16*) (ws + 64 * MB);  // [64,96) W:L2 R:L4
  bf16*  ff_b   = (bf16*) (ws + 72 * MB);  // [72,96) W:L10 R:L11
  bf16*  Atrig2 = (bf16*) (ws + 96 * MB);  // [96,101) W:L1 R:L4
  bf16*  Ttrig  = (bf16*) (ws + 101 * MB); // [101,102) W:L1 R:L2
  bf16*  CSb    = (bf16*) (ws + 102 * MB); // [102,112) W:L4 R:L5
  bf16*  qs2    = (bf16*) (ws + 96 * MB);  // [96,128) W:L6 R:L7
  bf16*  xenc_b = (bf16*) (ws + 128 * MB); // [128,136) W:L1 R:L2
  bf16*  BtK    = (bf16*) (ws + 136 * MB); // [136,138) W:L1 R:L2
  bf16*  BtV    = (bf16*) (ws + 138 * MB); // [138,140) W:L1 R:L2
  bf16*  xd_b   = (bf16*) (ws + 192 * MB); // [192,200) W:L5 R:L6,L8
  bf16*  x2_b   = (bf16*) (ws + 200 * MB); // [200,208) W:L8 R:L9,L11
  bf16*  gwT    = (bf16*) (ws + 208 * MB); // [208,216) W:L6 R:L7
  bf16*  Yt     = (bf16*) (ws + 216 * MB); // [216,232) W:L2 R:L3
  bf16*  gc     = (bf16*) (ws + 216 * MB); // [216,224) W:L4 R:L6 (Yt dead after L3)
  bf16*  Yf2    = (bf16*) (ws + 232 * MB); // [232,241) W:L3 R:L4
  bf16*  WoTh   = (bf16*) (ws + 241 * MB); // [241,243) W:L1 R:L6
  bf16*  W1T    = (bf16*) (ws + 243 * MB); // W:L1 R:L9
  bf16*  W2T    = (bf16*) (ws + 245 * MB); // W:L1 R:L10
  bf16*  xdec_b = (bf16*) (ws + 247 * MB); // [247,255) W:L1 R:L2

  // --- L1: prep ---
  prep_all<<<50752, 256, 0, stream>>>(x_dec, x_enc, Ttrig, Atrig2, xdec_b, xenc_b,
                                      Wq, Wk, Wv, Wo, W1, W2,
                                      BtQ, BtK, BtV, WoTh, W1T, W2T);

  // --- L2: K/V projection (transposed+softmaxed, LDS-coalesced stores) ∥ Yt DFT GEMM ---
  fused_kv_yt<<<2560, 256, 0, stream>>>(xenc_b, BtK, BtV, bk, bv, ksT, vsT,
                                        Ttrig, xdec_b, Yt);

  // --- L3: fold ---
  fold_y<<<17408, 256, 0, stream>>>(Yt, Yf2);

  // --- L4: gc GEMM  ∥  CS GEMM ---
  fused_gc_cs<<<1088, 256, 0, stream>>>(ksT, vsT, gc, Atrig2, Yf2, CSb);

  // --- L5: LN1 ---
  ln1_kernel<<<8192, 256, 0, stream>>>(x_dec, CSb, g1, be1, xd_b);

  // --- L6: Q projection+softmax  ∥  gwT ---
  fused_q_gw<<<1536, 256, 0, stream>>>(xd_b, BtQ, bq, qs2, WoTh, gc, gwT);

  // --- L7: attn = qs2 . gwT^T + bo ---
  gemm_bt<64, 0, 1, 0, 0, 1><<<512, 256, 0, stream>>>(
      qs2, gwT, bo, attn_b, 512, 2048, 4194304L, 1048576L, 0L, 1048576L, 8, 16, 32);
  // --- L8: LN2 ---
  ln_kernel<bf16, bf16, 1, 0><<<8192, 256, 0, stream>>>(
      xd_b, attn_b, g2, be2, x2_b, nullptr);

  // --- L9: FFN W1 + SELU ---
  gemm_bt<128, 0, 1, 1, 0, 1><<<1024, 256, 0, stream>>>(
      x2_b, W1T, b1, midb, 2048, 512, 0L, 0L, 0L, 0L, 16, 64, 16);
  // --- L10: FFN W2 ---
  gemm_bt<64, 0, 1, 0, 0, 1><<<512, 256, 0, stream>>>(
      midb, W2T, b2, ff_b, 512, 2048, 0L, 0L, 0L, 0L, 8, 64, 8);
  // --- L11: LN3 -> output (f32) ---
  ln_kernel<bf16, bf16, 0, 1><<<8192, 256, 0, stream>>>(
      x2_b, ff_b, g3, be3, nullptr, (float*)d_out);
}

// Round 12
// 366.595 us; speedup vs baseline: 1.1204x; 1.0337x over previous
//
#include <hip/hip_runtime.h>
#include <stdint.h>

typedef __bf16 bf16;
typedef __bf16 bf16x8 __attribute__((ext_vector_type(8)));
typedef float f32x4 __attribute__((ext_vector_type(4)));

// ---------------- async global->LDS (16B per lane) ----------------
static __device__ __forceinline__ void async16(const void* g, void* l) {
  __builtin_amdgcn_global_load_lds(
      (__attribute__((address_space(1))) void*)g,
      (__attribute__((address_space(3))) void*)l, 16, 0, 0);
}

// ---------------- merged prep ----------------
// blocks [0,2048) Ttrig | [2048,11840) Atrig2 (cos|sin half-DFT, K=1088) |
// [11840,15936) cast x_dec (x4 vectorized) | [15936,20032) cast x_enc (x4) |
// [20032,26176) weight transposes
// BtQ/BtK/BtV ALL use the h-in-bits-4:5 permuted row order n=(e&15)|(h<<4)|((e>>4)<<6)
// so the QKV epilogue gets h==ni: register-axis softmax (Q,K) and register-local
// transposed stores (K,V).
__global__ void __launch_bounds__(256) prep_all(
    const float* __restrict__ xdec, const float* __restrict__ xenc,
    bf16* __restrict__ Ttrig, bf16* __restrict__ Atrig2,
    bf16* __restrict__ xdec_b, bf16* __restrict__ xenc_b,
    const float* __restrict__ Wq, const float* __restrict__ Wk,
    const float* __restrict__ Wv, const float* __restrict__ Wo,
    const float* __restrict__ W1, const float* __restrict__ W2,
    bf16* __restrict__ BtQ, bf16* __restrict__ BtK, bf16* __restrict__ BtV,
    bf16* __restrict__ WoTh, bf16* __restrict__ W1T, bf16* __restrict__ W2T) {
  __shared__ bf16 tile[32][33];
  int id = blockIdx.x;
  if (id < 2048) {                     // Ttrig[1024][512]
    int idx = id * 256 + threadIdx.x;
    int d = idx & 511, jp = idx >> 9;
    int jj = jp >> 1, p = jp & 1;
    int t = (d * jj) & 511;
    float ang = (float)t * (6.283185307179586f / 512.0f);
    Ttrig[idx] = (bf16)(p ? __sinf(ang) : __cosf(ang));
  } else if (id < 11840) {             // Atrig2[2][1152][1088]: half 0 cos, half 1 -sin
    int idx = (id - 2048) * 256 + threadIdx.x;   // < 2506752
    int k = idx % 1088;
    int rr = idx / 1088;
    int r = rr % 1152, half = rr / 1152;
    float v = 0.0f;
    int tt = (r * k) & 2047;
    float ang = (float)tt * (6.283185307179586f / 2048.0f);
    if (half == 0) { if (r <= 1024 && k <= 1024) v = __cosf(ang); }
    else           { if (r <= 1023 && k >= 1 && k <= 1023) v = -__sinf(ang); }
    Atrig2[idx] = (bf16)v;
  } else if (id < 15936) {             // cast x_dec, 4 elems/thread
    int i = ((id - 11840) * 256 + threadIdx.x) * 4;
    float4 v = *(const float4*)(xdec + i);
    bf16 o[4] __attribute__((aligned(8))) =
        {(bf16)v.x, (bf16)v.y, (bf16)v.z, (bf16)v.w};
    *(uint2*)(xdec_b + i) = *(const uint2*)o;
  } else if (id < 20032) {             // cast x_enc, 4 elems/thread
    int i = ((id - 15936) * 256 + threadIdx.x) * 4;
    float4 v = *(const float4*)(xenc + i);
    bf16 o[4] __attribute__((aligned(8))) =
        {(bf16)v.x, (bf16)v.y, (bf16)v.z, (bf16)v.w};
    *(uint2*)(xenc_b + i) = *(const uint2*)o;
  } else {
    int id2 = id - 20032;
    int kind = id2 >> 10, t = id2 & 1023;
    const float* in; bf16* out; int R, C, rt, ct;
    bool iperm = false, hsel = false; int hh = 0;
    if (kind == 0)      { in = Wq; out = BtQ; R = 2048; C = 512; rt = t >> 4; ct = t & 15; iperm = true; }
    else if (kind == 1) { in = Wk; out = BtK; R = 2048; C = 512; rt = t >> 4; ct = t & 15; iperm = true; }
    else if (kind == 2) { in = Wv; out = BtV; R = 2048; C = 512; rt = t >> 4; ct = t & 15; iperm = true; }
    else if (kind == 3) {              // WoTh[h][n][e] = Wo[4e+h][n]
      int zz = t >> 8, tt = t & 255;
      in = Wo; out = WoTh + (long)zz * 262144;
      R = 512; C = 512; rt = tt >> 4; ct = tt & 15; hsel = true; hh = zz;
    }
    else if (kind == 4) { in = W1; out = W1T; R = 512; C = 2048; rt = t >> 6; ct = t & 63; }
    else                { in = W2; out = W2T; R = 2048; C = 512; rt = t >> 4; ct = t & 15; }
    int c0 = ct * 32, r0 = rt * 32;
    int tx = threadIdx.x & 31, ty = threadIdx.x >> 5;
#pragma unroll
    for (int i = 0; i < 32; i += 8) {
      int r = r0 + ty + i;
      int rr = hsel ? (4 * r + hh) : r;
      tile[ty + i][tx] = (bf16)in[(long)rr * C + (c0 + tx)];
    }
    __syncthreads();
#pragma unroll
    for (int i = 0; i < 32; i += 8) {
      int cc = c0 + ty + i, rr = r0 + tx;
      if (iperm) {  // Bt row from W row h*512+din; cc = e, rr>>9 = h, rr&511 = din
        int e = cc, h = rr >> 9;
        int n = (e & 15) | (h << 4) | ((e >> 4) << 6);
        out[((long)n << 9) + (rr & 511)] = tile[tx][ty + i];
      } else {
        out[(long)cc * R + rr] = tile[tx][ty + i];
      }
    }
  }
}

// Fold Yt [4][512][4096] -> Yf2 [8][512][1088], 2 elems/thread (8704 blocks).
// z<4 cos-fold: k=0 -> Y[0]; k=1024 -> Y[1024]; 0<k<1024 -> Y[k]+Y[2048-k]; else 0.
// z>=4 sin-fold: 1<=k<=1023 -> Y[2048+k]-Y[4096-k]; else 0.
__global__ void __launch_bounds__(256) fold_y(const bf16* __restrict__ Yt,
                                              bf16* __restrict__ Yf2) {
  int idx2 = blockIdx.x * 256 + threadIdx.x;   // 2228224 = 8*512*544
  int k2 = (idx2 % 544) * 2;
  int rr = idx2 / 544;
  int j = rr & 511, z = rr >> 9;
  int b = z & 3, half = z >> 2;
  const bf16* yin = Yt + (long)b * 2097152 + (long)j * 4096;
  bf16 o[2] __attribute__((aligned(4)));
  if (half == 0) {
    bf16 f[2] __attribute__((aligned(4)));
    *(uint*)f = *(const uint*)(yin + k2);        // Y[k2], Y[k2+1]
    float r0 = (float)yin[2048 - k2];            // partner of k2 (k2=0: unused)
    float r1 = (float)yin[2047 - k2];            // partner of k2+1
    float v0, v1;
    if (k2 == 0)            v0 = (float)f[0];
    else if (k2 == 1024)    v0 = (float)f[0];
    else if (k2 < 1024)     v0 = (float)f[0] + r0;
    else                    v0 = 0.0f;
    if (k2 + 1 < 1024)      v1 = (float)f[1] + r1;
    else                    v1 = 0.0f;
    o[0] = (bf16)v0; o[1] = (bf16)v1;
  } else {
    bf16 f[2] __attribute__((aligned(4)));
    *(uint*)f = *(const uint*)(yin + 2048 + k2); // Ys[k2], Ys[k2+1]
    float r0 = (float)yin[4096 - k2];            // k2=0: unused
    float r1 = (float)yin[4095 - k2];
    float v0, v1;
    if (k2 >= 1 && k2 <= 1023) v0 = (float)f[0] - r0; else v0 = 0.0f;
    if (k2 + 1 <= 1023)        v1 = (float)f[1] - r1; else v1 = 0.0f;
    o[0] = (bf16)v0; o[1] = (bf16)v1;
  }
  *(uint*)(Yf2 + (long)z * 557056 + (long)j * 1088 + k2) = *(const uint*)o;
}

// ---------------- LN1 with DFT recombination (pairwise vectorized) ----------------
__global__ void __launch_bounds__(256) ln1_kernel(
    const float* __restrict__ xdec, const bf16* __restrict__ CSb,
    const float* __restrict__ g, const float* __restrict__ be,
    bf16* __restrict__ outb) {
  const int row = blockIdx.x, t = threadIdx.x;
  const int b = row >> 11, s = row & 2047;
  const int sp = (s <= 1024) ? s : 2048 - s;
  const float sgn = (s <= 1024) ? 1.0f : -1.0f;
  const bf16* Crow = CSb + ((long)b * 1152 + sp) * 512;
  const bf16* Srow = CSb + ((long)(b + 4) * 1152 + sp) * 512;
  const long base = (long)row * 512;
  float2 xp = *(const float2*)(xdec + base + 2 * t);
  bf16 cp[2] __attribute__((aligned(4)));
  bf16 spv[2] __attribute__((aligned(4)));
  *(uint*)cp = *(const uint*)(Crow + 2 * t);
  *(uint*)spv = *(const uint*)(Srow + 2 * t);
  float v0 = xp.x + (float)cp[0] + sgn * (float)spv[0];
  float v1 = xp.y + (float)cp[1] + sgn * (float)spv[1];
  float sm = v0 + v1, q = v0 * v0 + v1 * v1;
#pragma unroll
  for (int off = 32; off > 0; off >>= 1) {
    sm += __shfl_down(sm, off);
    q += __shfl_down(q, off);
  }
  __shared__ float red[8];
  const int wv = t >> 6, ln = t & 63;
  if (ln == 0) { red[wv] = sm; red[wv + 4] = q; }
  __syncthreads();
  float S = red[0] + red[1] + red[2] + red[3];
  float Q = red[4] + red[5] + red[6] + red[7];
  float mu = S * (1.0f / 512.0f);
  float var = Q * (1.0f / 512.0f) - mu * mu;
  float rstd = rsqrtf(var + 1e-5f);
  float2 gp = *(const float2*)(g + 2 * t);
  float2 bp = *(const float2*)(be + 2 * t);
  bf16 op[2] __attribute__((aligned(4)));
  op[0] = (bf16)(gp.x * (v0 - mu) * rstd + bp.x);
  op[1] = (bf16)(gp.y * (v1 - mu) * rstd + bp.y);
  *(uint*)(outb + base + 2 * t) = *(const uint*)op;
}

// ---------------- generic LayerNorm (bf16+bf16 in, pairwise vectorized) ----------------
template <int WRITE_BF16, int WRITE_F32>
__global__ void __launch_bounds__(256) ln_kernel(
    const bf16* __restrict__ A, const bf16* __restrict__ Bv,
    const float* __restrict__ g, const float* __restrict__ be,
    bf16* __restrict__ outb, float* __restrict__ outf) {
  const int row = blockIdx.x, t = threadIdx.x;
  const long base = (long)row * 512;
  bf16 ap[2] __attribute__((aligned(4)));
  bf16 bpv[2] __attribute__((aligned(4)));
  *(uint*)ap = *(const uint*)(A + base + 2 * t);
  *(uint*)bpv = *(const uint*)(Bv + base + 2 * t);
  float v0 = (float)ap[0] + (float)bpv[0];
  float v1 = (float)ap[1] + (float)bpv[1];
  float s = v0 + v1, q = v0 * v0 + v1 * v1;
#pragma unroll
  for (int off = 32; off > 0; off >>= 1) {
    s += __shfl_down(s, off);
    q += __shfl_down(q, off);
  }
  __shared__ float red[8];
  const int wv = t >> 6, ln = t & 63;
  if (ln == 0) { red[wv] = s; red[wv + 4] = q; }
  __syncthreads();
  float S = red[0] + red[1] + red[2] + red[3];
  float Q = red[4] + red[5] + red[6] + red[7];
  float mu = S * (1.0f / 512.0f);
  float var = Q * (1.0f / 512.0f) - mu * mu;
  float rstd = rsqrtf(var + 1e-5f);
  float2 gp = *(const float2*)(g + 2 * t);
  float2 bp = *(const float2*)(be + 2 * t);
  float o0 = gp.x * (v0 - mu) * rstd + bp.x;
  float o1 = gp.y * (v1 - mu) * rstd + bp.y;
  if (WRITE_BF16) {
    bf16 op[2] __attribute__((aligned(4)));
    op[0] = (bf16)o0; op[1] = (bf16)o1;
    *(uint*)(outb + base + 2 * t) = *(const uint*)op;
  }
  if (WRITE_F32) {
    float2 of; of.x = o0; of.y = o1;
    *(float2*)(outf + base + 2 * t) = of;
  }
}

// ---------------- GEMM body: C = A[M,K] * Bt[N,K]^T (single-buffer m97 K-loop) ---------
// SWIZ: 0 plain; 1 group-by-y; 2 group-by-z; 3 group-by-x. gin = blocks per group.
// ADDR_MODE: 0 plain (sCz*z); 9 gw out (col&15)|(h<<4)|((col>>4)<<6).
// HAS_BIAS: 0 none, 1 bias[sBiasz*z+col].
// AHEAD: 0 A+=sAz*z; 1 A+=sAz*(z&3); 2 A+=sAz*(z>>2).
template <int BN, int ADDR_MODE, int HAS_BIAS, int DO_SELU, int F32OUT, int SWIZ,
          int AHEAD>
static __device__ __forceinline__ void gemm_bt_body(
    int id, bf16* lA, bf16* lB,
    const bf16* __restrict__ A, const bf16* __restrict__ Bt,
    const float* __restrict__ bias, void* __restrict__ Cout,
    int N, int K, long sAz, long sBz, long sBiasz, long sCz,
    int gx, int gy, int gin) {
  int x, y, z;
  {
    if (SWIZ == 0) {
      x = id % gx; int t2 = id / gx; y = t2 % gy; z = t2 / gy;
    } else {
      int xcd = id & 7, r = id >> 3;
      int inner = r % gin, G = xcd + 8 * (r / gin);
      if (SWIZ == 1)      { y = G; x = inner % gx; z = inner / gx; }
      else if (SWIZ == 2) { z = G; x = inner % gx; y = inner / gx; }
      else                { x = G; y = inner % gy; z = inner / gy; }
    }
  }
  A  += (AHEAD == 1) ? sAz * (z & 3) : (AHEAD == 2) ? sAz * (z >> 2) : sAz * z;
  Bt += sBz * z;
  const int m0 = y * 128, n0 = x * BN;
  const int t = threadIdx.x;
  const int lane = t & 63, wave = t >> 6;
  const int srow = t >> 3;
  const int pch  = t & 7;
  const int lch  = pch ^ (srow & 7);   // XOR bank swizzle (global-side)
  const bf16* Ag = A  + (long)(m0 + srow) * K + lch * 8;
  const bf16* Bg = Bt + (long)(n0 + srow) * K + lch * 8;
  bf16* lAp = lA + srow * 64 + pch * 8;
  bf16* lBp = lB + srow * 64 + pch * 8;
  constexpr int MI = (BN == 128) ? 4 : 2;
  const int wm = (BN == 128) ? (wave >> 1) * 64 : wave * 32;
  const int wn = (BN == 128) ? (wave & 1) * 64 : 0;
  const int fr = lane & 15, fq = lane >> 4;

  f32x4 acc[MI][4] = {};

  for (int k0 = 0; k0 < K; k0 += 64) {
    __syncthreads();
#pragma unroll
    for (int i = 0; i < 4; ++i)
      async16(Ag + k0 + (long)(32 * i) * K, lAp + 32 * i * 64);
#pragma unroll
    for (int i = 0; i < BN / 32; ++i)
      async16(Bg + k0 + (long)(32 * i) * K, lBp + 32 * i * 64);
    __syncthreads();
#pragma unroll
    for (int kk = 0; kk < 2; ++kk) {
      bf16x8 av[MI], bfrag[4];
#pragma unroll
      for (int mi = 0; mi < MI; ++mi) {
        int r = wm + mi * 16 + fr;
        int c = (kk * 4 + fq) ^ (r & 7);
        av[mi] = *(const bf16x8*)&lA[r * 64 + c * 8];
      }
#pragma unroll
      for (int ni = 0; ni < 4; ++ni) {
        int r = wn + ni * 16 + fr;
        int c = (kk * 4 + fq) ^ (r & 7);
        bfrag[ni] = *(const bf16x8*)&lB[r * 64 + c * 8];
      }
#pragma unroll
      for (int mi = 0; mi < MI; ++mi)
#pragma unroll
        for (int ni = 0; ni < 4; ++ni)
          acc[mi][ni] = __builtin_amdgcn_mfma_f32_16x16x32_bf16(
              av[mi], bfrag[ni], acc[mi][ni], 0, 0, 0);
    }
  }

  // epilogue: C/D layout col = lane&15, row = (lane>>4)*4 + reg
#pragma unroll
  for (int mi = 0; mi < MI; ++mi) {
#pragma unroll
    for (int ni = 0; ni < 4; ++ni) {
      const int col = n0 + wn + ni * 16 + fr;
      float bias_v = 0.0f;
      if (HAS_BIAS == 1) bias_v = bias[sBiasz * z + col];
      if (ADDR_MODE == 9) {                  // z=b*4+h -> Bt_b[row][(col&15)|(h<<4)|((col>>4)<<6)]
        const int b = z >> 2, h = z & 3;
        const int kidx = (col & 15) | (h << 4) | ((col >> 4) << 6);
#pragma unroll
        for (int r = 0; r < 4; ++r) {
          const int row = m0 + wm + mi * 16 + fq * 4 + r;
          ((bf16*)Cout)[((long)(b * 512 + row)) * 2048 + kidx] =
              (bf16)(acc[mi][ni][r] + bias_v);
        }
      } else {
#pragma unroll
        for (int r = 0; r < 4; ++r) {
          const int row = m0 + wm + mi * 16 + fq * 4 + r;
          float v = acc[mi][ni][r] + bias_v;
          if (DO_SELU) v = v > 0.0f ? 1.0507009873554805f * v
                                    : 1.7580993408473766f * (__expf(v) - 1.0f);
          long addr = sCz * z + (long)row * N + col;
          if (F32OUT) ((float*)Cout)[addr] = v;
          else        ((bf16*)Cout)[addr] = (bf16)v;
        }
      }
    }
  }
}

// standalone wrapper
template <int BN, int ADDR_MODE, int HAS_BIAS, int DO_SELU, int F32OUT, int SWIZ,
          int AHEAD = 0>
__global__ void __launch_bounds__(256, 2) gemm_bt(
    const bf16* __restrict__ A, const bf16* __restrict__ Bt,
    const float* __restrict__ bias, void* __restrict__ Cout,
    int N, int K, long sAz, long sBz, long sBiasz, long sCz,
    int gx, int gy, int gin) {
  __shared__ __align__(16) bf16 lA[128 * 64];
  __shared__ __align__(16) bf16 lB[BN * 64];
  gemm_bt_body<BN, ADDR_MODE, HAS_BIAS, DO_SELU, F32OUT, SWIZ, AHEAD>(
      blockIdx.x, lA, lB, A, Bt, bias, Cout, N, K, sAz, sBz, sBiasz, sCz, gx, gy, gin);
}

// ---------------- Q/K/V projection GEMM body (id in [0,3072), uniform segments) --------
// All three B-matrices use the permuted row order -> h == ni in the epilogue.
// seg 0 (Q): register-axis head-softmax, writes qs2 (kidx layout, coalesced).
// seg 1 (K): register-axis head-softmax, transposed store via LDS -> 256B-coalesced.
// seg 2 (V): transposed store via LDS (no softmax).
// NOTE: lA must point at a contiguous 32 KiB (lB = lA+8192); segs 1/2 reuse it as the
// 128x128 transpose buffer after the K-loop.
static __device__ __forceinline__ void qkv_body(
    int id, bf16* lA, bf16* lB,
    const bf16* __restrict__ Aq, const bf16* __restrict__ Aenc,
    const bf16* __restrict__ BQ, const bf16* __restrict__ BK,
    const bf16* __restrict__ BV,
    const float* __restrict__ bq, const float* __restrict__ bk,
    const float* __restrict__ bv,
    bf16* __restrict__ qs2, bf16* __restrict__ ksT, bf16* __restrict__ vsT) {
  const int seg = id >> 10, sid = id & 1023;
  const int xcd = sid & 7, r = sid >> 3;
  const int x = r & 15, y = xcd + 8 * (r >> 4);
  const bf16 *A, *Bt; bf16* out; const float* bias;
  if (seg == 0)      { A = Aq;   Bt = BQ; out = qs2; bias = bq; }
  else if (seg == 1) { A = Aenc; Bt = BK; out = ksT; bias = bk; }
  else               { A = Aenc; Bt = BV; out = vsT; bias = bv; }
  const int K = 512;
  const int m0 = y * 128, n0 = x * 128;
  const int t = threadIdx.x;
  const int lane = t & 63, wave = t >> 6;
  const int srow = t >> 3, pch = t & 7, lch = pch ^ (srow & 7);
  const bf16* Ag = A  + (long)(m0 + srow) * K + lch * 8;
  const bf16* Bg = Bt + (long)(n0 + srow) * K + lch * 8;
  bf16* lAp = lA + srow * 64 + pch * 8;
  bf16* lBp = lB + srow * 64 + pch * 8;
  const int wm = (wave >> 1) * 64, wn = (wave & 1) * 64;
  const int fr = lane & 15, fq = lane >> 4;

  f32x4 acc[4][4] = {};
  for (int k0 = 0; k0 < K; k0 += 64) {
    __syncthreads();
#pragma unroll
    for (int i = 0; i < 4; ++i) {
      async16(Ag + k0 + (long)(32 * i) * K, lAp + 32 * i * 64);
      async16(Bg + k0 + (long)(32 * i) * K, lBp + 32 * i * 64);
    }
    __syncthreads();
#pragma unroll
    for (int kk = 0; kk < 2; ++kk) {
      bf16x8 av[4], bfrag[4];
#pragma unroll
      for (int mi = 0; mi < 4; ++mi) {
        int rr = wm + mi * 16 + fr;
        int c = (kk * 4 + fq) ^ (rr & 7);
        av[mi] = *(const bf16x8*)&lA[rr * 64 + c * 8];
      }
#pragma unroll
      for (int ni = 0; ni < 4; ++ni) {
        int rr = wn + ni * 16 + fr;
        int c = (kk * 4 + fq) ^ (rr & 7);
        bfrag[ni] = *(const bf16x8*)&lB[rr * 64 + c * 8];
      }
#pragma unroll
      for (int mi = 0; mi < 4; ++mi)
#pragma unroll
        for (int ni = 0; ni < 4; ++ni)
          acc[mi][ni] = __builtin_amdgcn_mfma_f32_16x16x32_bf16(
              av[mi], bfrag[ni], acc[mi][ni], 0, 0, 0);
    }
  }

  // h == ni; feature index e = fr + 16*((n0+wn)>>6). Bias is bias[ni*512+e].
  const int ebase = fr + 16 * ((n0 + wn) >> 6);
  const float b0 = bias[ebase], b1 = bias[512 + ebase],
              b2 = bias[1024 + ebase], b3 = bias[1536 + ebase];
  if (seg == 0) {
#pragma unroll
    for (int mi = 0; mi < 4; ++mi) {
#pragma unroll
      for (int r = 0; r < 4; ++r) {
        const int row = m0 + wm + mi * 16 + fq * 4 + r;
        float v0 = acc[mi][0][r] + b0;
        float v1 = acc[mi][1][r] + b1;
        float v2 = acc[mi][2][r] + b2;
        float v3 = acc[mi][3][r] + b3;
        float m = fmaxf(fmaxf(v0, v1), fmaxf(v2, v3));
        float p0 = __expf(v0 - m), p1 = __expf(v1 - m),
              p2 = __expf(v2 - m), p3 = __expf(v3 - m);
        float rs = 1.0f / (p0 + p1 + p2 + p3);
        const long ob = (long)row * 2048 + n0 + wn + fr;
        out[ob]      = (bf16)(p0 * rs);
        out[ob + 16] = (bf16)(p1 * rs);
        out[ob + 32] = (bf16)(p2 * rs);
        out[ob + 48] = (bf16)(p3 * rs);
      }
    }
  } else {
    // Transposed store via LDS: block tile = rows (h*32+e_loc) in [0,128) x s in [0,128).
    // XOR-swizzle 16B chunks by (row&15): write uint2 (aligned-4 within one 8-chunk),
    // read uint4 -> 256B-contiguous global stores. <=2-way LDS conflicts (free, m136).
    bf16* lT = lA;                         // lA/lB contiguous 32 KiB = 128x128 bf16
    const int bb = m0 >> 11;
    const int s_tile = m0 & 2047;
    const int e_loc = fr + 16 * (wn >> 6); // [0,32)
    __syncthreads();                       // all waves done with lA/lB ds_reads
#pragma unroll
    for (int mi = 0; mi < 4; ++mi) {
      const int s0 = wm + mi * 16 + fq * 4;   // [0,128), multiple of 4
      bf16 tmp[4][4] __attribute__((aligned(8)));   // [h][r]
#pragma unroll
      for (int r = 0; r < 4; ++r) {
        float v0 = acc[mi][0][r] + b0;
        float v1 = acc[mi][1][r] + b1;
        float v2 = acc[mi][2][r] + b2;
        float v3 = acc[mi][3][r] + b3;
        if (seg == 1) {   // K: head softmax
          float m = fmaxf(fmaxf(v0, v1), fmaxf(v2, v3));
          float p0 = __expf(v0 - m), p1 = __expf(v1 - m),
                p2 = __expf(v2 - m), p3 = __expf(v3 - m);
          float rs = 1.0f / (p0 + p1 + p2 + p3);
          v0 = p0 * rs; v1 = p1 * rs; v2 = p2 * rs; v3 = p3 * rs;
        }
        tmp[0][r] = (bf16)v0; tmp[1][r] = (bf16)v1;
        tmp[2][r] = (bf16)v2; tmp[3][r] = (bf16)v3;
      }
#pragma unroll
      for (int ni = 0; ni < 4; ++ni) {
        const int row = ni * 32 + e_loc;   // [0,128)
        const int el = row * 128 + ((((s0 >> 3) ^ (row & 15)) << 3) | (s0 & 7));
        *(uint2*)&lT[el] = *(const uint2*)tmp[ni];
      }
    }
    __syncthreads();
    const int c = lane & 15, rg = lane >> 4;   // chunk idx, row-group
#pragma unroll
    for (int i = 0; i < 8; ++i) {
      const int row = wave * 32 + rg + i * 4;  // [0,128)
      const int el = row * 128 + ((c ^ (row & 15)) << 3);
      uint4 v = *(const uint4*)&lT[el];
      const int h = row >> 5, e = (row & 31) + 32 * x;
      *(uint4*)(out + ((long)((bb * 4 + h) * 512 + e)) * 2048 + s_tile + c * 8) = v;
    }
  }
}

// ---------------- fused launches ----------------
// [0,2048): K/V projection (writes ksT/vsT transposed) | [2048,2560): Yt DFT GEMM
__global__ void __launch_bounds__(256, 2) fused_kv_yt(
    const bf16* __restrict__ Aenc, const bf16* __restrict__ BK,
    const bf16* __restrict__ BV,
    const float* __restrict__ bk, const float* __restrict__ bv,
    bf16* __restrict__ ksT, bf16* __restrict__ vsT,
    const bf16* __restrict__ Ttrig, const bf16* __restrict__ xdec_b,
    bf16* __restrict__ Yt) {
  __shared__ __align__(16) bf16 smem[16384];   // 32 KiB
  int id = blockIdx.x;
  if (id < 2048)
    qkv_body(id + 1024, smem, smem + 8192, nullptr, Aenc, nullptr, BK, BV,
             nullptr, bk, bv, nullptr, ksT, vsT);
  else
    gemm_bt_body<128, 0, 0, 0, 0, 3, 0>(id - 2048, smem, smem + 8192,
        Ttrig, xdec_b, nullptr, Yt, 2048, 512, 0L, 1048576L, 0L, 2097152L, 16, 8, 32);
}

// [0,512): gc GEMM | [512,1088): CS GEMM
__global__ void __launch_bounds__(256, 2) fused_gc_cs(
    const bf16* __restrict__ ksT, const bf16* __restrict__ vsT,
    bf16* __restrict__ gc,
    const bf16* __restrict__ Atrig2, const bf16* __restrict__ Yf2,
    bf16* __restrict__ CSb) {
  __shared__ __align__(16) bf16 smem[12288];   // 24 KiB
  int id = blockIdx.x;
  if (id < 512)
    gemm_bt_body<64, 0, 0, 0, 0, 2, 0>(id, smem, smem + 8192,
        ksT, vsT, nullptr, gc, 512, 2048, 1048576L, 1048576L, 0L, 262144L, 8, 4, 32);
  else
    gemm_bt_body<64, 0, 0, 0, 0, 2, 2>(id - 512, smem, smem + 8192,
        Atrig2, Yf2, nullptr, CSb, 512, 1088, 1253376L, 557056L, 0L, 589824L, 8, 9, 72);
}

// [0,1024): Q projection + head-softmax | [1024,1536): gwT GEMM (kidx layout)
__global__ void __launch_bounds__(256, 2) fused_q_gw(
    const bf16* __restrict__ Aq, const bf16* __restrict__ BQ,
    const float* __restrict__ bq, bf16* __restrict__ qs2,
    const bf16* __restrict__ WoTh, const bf16* __restrict__ gc,
    bf16* __restrict__ gwT) {
  __shared__ __align__(16) bf16 smem[16384];   // 32 KiB
  int id = blockIdx.x;
  if (id < 1024)
    qkv_body(id, smem, smem + 8192, Aq, nullptr, BQ, nullptr, nullptr,
             bq, nullptr, nullptr, qs2, nullptr, nullptr);
  else
    gemm_bt_body<64, 9, 0, 0, 0, 2, 1>(id - 1024, smem, smem + 8192,
        WoTh, gc, nullptr, gwT, 512, 512, 262144L, 262144L, 0L, 0L, 8, 4, 32);
}

// ---------------- launcher ----------------
extern "C" void kernel_launch(void* const* d_in, const int* in_sizes, int n_in,
                              void* d_out, int out_size, void* d_ws, size_t ws_size,
                              hipStream_t stream) {
  (void)in_sizes; (void)n_in; (void)out_size; (void)ws_size;
  const float* x_enc = (const float*)d_in[0];
  const float* x_dec = (const float*)d_in[1];
  const float* Wq = (const float*)d_in[2];
  const float* bq = (const float*)d_in[3];
  const float* Wk = (const float*)d_in[4];
  const float* bk = (const float*)d_in[5];
  const float* Wv = (const float*)d_in[6];
  const float* bv = (const float*)d_in[7];
  const float* Wo = (const float*)d_in[8];
  const float* bo = (const float*)d_in[9];
  const float* g1 = (const float*)d_in[10];
  const float* be1 = (const float*)d_in[11];
  const float* g2 = (const float*)d_in[12];
  const float* be2 = (const float*)d_in[13];
  const float* W1 = (const float*)d_in[14];
  const float* b1 = (const float*)d_in[15];
  const float* W2 = (const float*)d_in[16];
  const float* b2 = (const float*)d_in[17];
  const float* g3 = (const float*)d_in[18];
  const float* be3 = (const float*)d_in[19];

  char* ws = (char*)d_ws;
  const size_t MB = 1u << 20;
  // time-disjoint aliasing, peak 255 MiB. Launch order:
  // L1 prep | L2 kv+yt | L3 fold | L4 gc+cs | L5 ln1 | L6 q+gw | L7 attn
  // L8 ln2 | L9 w1 | L10 w2 | L11 ln3
  bf16*  BtQ    = (bf16*) (ws + 0);        // [0,2)   W:L1 R:L6
  bf16*  midb   = (bf16*) (ws + 0);        // [0,32)  W:L9 R:L10
  bf16*  ksT    = (bf16*) (ws + 32 * MB);  // [32,64) W:L2 R:L4
  bf16*  attn_b = (bf16*) (ws + 32 * MB);  // [32,64) W:L7 R:L8
  bf16*  vsT    = (bf16*) (ws + 64 * MB);  // [64,96) W:L2 R:L4
  bf16*  ff_b   = (bf16*) (ws + 72 * MB);  // [72,96) W:L10 R:L11
  bf16*  Atrig2 = (bf16*) (ws + 96 * MB);  // [96,101) W:L1 R:L4
  bf16*  Ttrig  = (bf16*) (ws + 101 * MB); // [101,102) W:L1 R:L2
  bf16*  CSb    = (bf16*) (ws + 102 * MB); // [102,112) W:L4 R:L5
  bf16*  qs2    = (bf16*) (ws + 96 * MB);  // [96,128) W:L6 R:L7
  bf16*  xenc_b = (bf16*) (ws + 128 * MB); // [128,136) W:L1 R:L2
  bf16*  BtK    = (bf16*) (ws + 136 * MB); // [136,138) W:L1 R:L2
  bf16*  BtV    = (bf16*) (ws + 138 * MB); // [138,140) W:L1 R:L2
  bf16*  xd_b   = (bf16*) (ws + 192 * MB); // [192,200) W:L5 R:L6,L8
  bf16*  x2_b   = (bf16*) (ws + 200 * MB); // [200,208) W:L8 R:L9,L11
  bf16*  gwT    = (bf16*) (ws + 208 * MB); // [208,216) W:L6 R:L7
  bf16*  Yt     = (bf16*) (ws + 216 * MB); // [216,232) W:L2 R:L3
  bf16*  gc     = (bf16*) (ws + 216 * MB); // [216,224) W:L4 R:L6 (Yt dead after L3)
  bf16*  Yf2    = (bf16*) (ws + 232 * MB); // [232,241) W:L3 R:L4
  bf16*  WoTh   = (bf16*) (ws + 241 * MB); // [241,243) W:L1 R:L6
  bf16*  W1T    = (bf16*) (ws + 243 * MB); // W:L1 R:L9
  bf16*  W2T    = (bf16*) (ws + 245 * MB); // W:L1 R:L10
  bf16*  xdec_b = (bf16*) (ws + 247 * MB); // [247,255) W:L1 R:L2

  // --- L1: prep ---
  prep_all<<<26176, 256, 0, stream>>>(x_dec, x_enc, Ttrig, Atrig2, xdec_b, xenc_b,
                                      Wq, Wk, Wv, Wo, W1, W2,
                                      BtQ, BtK, BtV, WoTh, W1T, W2T);

  // --- L2: K/V projection (transposed+softmaxed, LDS-coalesced stores) ∥ Yt DFT GEMM ---
  fused_kv_yt<<<2560, 256, 0, stream>>>(xenc_b, BtK, BtV, bk, bv, ksT, vsT,
                                        Ttrig, xdec_b, Yt);

  // --- L3: fold (2 elems/thread) ---
  fold_y<<<8704, 256, 0, stream>>>(Yt, Yf2);

  // --- L4: gc GEMM  ∥  CS GEMM ---
  fused_gc_cs<<<1088, 256, 0, stream>>>(ksT, vsT, gc, Atrig2, Yf2, CSb);

  // --- L5: LN1 ---
  ln1_kernel<<<8192, 256, 0, stream>>>(x_dec, CSb, g1, be1, xd_b);

  // --- L6: Q projection+softmax  ∥  gwT ---
  fused_q_gw<<<1536, 256, 0, stream>>>(xd_b, BtQ, bq, qs2, WoTh, gc, gwT);

  // --- L7: attn = qs2 . gwT^T + bo ---
  gemm_bt<64, 0, 1, 0, 0, 1><<<512, 256, 0, stream>>>(
      qs2, gwT, bo, attn_b, 512, 2048, 4194304L, 1048576L, 0L, 1048576L, 8, 16, 32);
  // --- L8: LN2 ---
  ln_kernel<1, 0><<<8192, 256, 0, stream>>>(
      xd_b, attn_b, g2, be2, x2_b, nullptr);

  // --- L9: FFN W1 + SELU ---
  gemm_bt<128, 0, 1, 1, 0, 1><<<1024, 256, 0, stream>>>(
      x2_b, W1T, b1, midb, 2048, 512, 0L, 0L, 0L, 0L, 16, 64, 16);
  // --- L10: FFN W2 ---
  gemm_bt<64, 0, 1, 0, 0, 1><<<512, 256, 0, stream>>>(
      midb, W2T, b2, ff_b, 512, 2048, 0L, 0L, 0L, 0L, 8, 64, 8);
  // --- L11: LN3 -> output (f32) ---
  ln_kernel<0, 1><<<8192, 256, 0, stream>>>(
      x2_b, ff_b, g3, be3, nullptr, (float*)d_out);
}

// Round 13
// 355.646 us; speedup vs baseline: 1.1549x; 1.0308x over previous
//
#include <hip/hip_runtime.h>
#include <stdint.h>

typedef __bf16 bf16;
typedef __bf16 bf16x8 __attribute__((ext_vector_type(8)));
typedef float f32x4 __attribute__((ext_vector_type(4)));

// ---------------- async global->LDS (16B per lane) ----------------
static __device__ __forceinline__ void async16(const void* g, void* l) {
  __builtin_amdgcn_global_load_lds(
      (__attribute__((address_space(1))) void*)g,
      (__attribute__((address_space(3))) void*)l, 16, 0, 0);
}

// ---------------- merged prep ----------------
// blocks [0,512) Ttrig x4 | [512,2960) Atrig2 x4 | [2960,7056) cast x_dec x4 |
// [7056,11152) cast x_enc x4 | [11152,17296) weight transposes
// BtQ/BtK/BtV ALL use the h-in-bits-4:5 permuted row order n=(e&15)|(h<<4)|((e>>4)<<6)
// so the QKV epilogue gets h==ni: register-axis softmax (Q,K) and register-local
// transposed stores (K,V).
__global__ void __launch_bounds__(256) prep_all(
    const float* __restrict__ xdec, const float* __restrict__ xenc,
    bf16* __restrict__ Ttrig, bf16* __restrict__ Atrig2,
    bf16* __restrict__ xdec_b, bf16* __restrict__ xenc_b,
    const float* __restrict__ Wq, const float* __restrict__ Wk,
    const float* __restrict__ Wv, const float* __restrict__ Wo,
    const float* __restrict__ W1, const float* __restrict__ W2,
    bf16* __restrict__ BtQ, bf16* __restrict__ BtK, bf16* __restrict__ BtV,
    bf16* __restrict__ WoTh, bf16* __restrict__ W1T, bf16* __restrict__ W2T) {
  __shared__ bf16 tile[32][33];
  int id = blockIdx.x;
  if (id < 512) {                      // Ttrig[1024][512], 4 d/thread
    int idx = id * 256 + threadIdx.x;  // < 131072
    int d0 = (idx & 127) * 4, jp = idx >> 7;
    int jj = jp >> 1, p = jp & 1;
    bf16 o[4] __attribute__((aligned(8)));
#pragma unroll
    for (int i = 0; i < 4; ++i) {
      int tt = ((d0 + i) * jj) & 511;
      float ang = (float)tt * (6.283185307179586f / 512.0f);
      o[i] = (bf16)(p ? __sinf(ang) : __cosf(ang));
    }
    *(uint2*)(Ttrig + jp * 512 + d0) = *(const uint2*)o;
  } else if (id < 2960) {              // Atrig2[2][1152][1088], 4 k/thread
    int idx = (id - 512) * 256 + threadIdx.x;   // < 626688
    int k0 = (idx % 272) * 4;
    int rr = idx / 272;
    int r = rr % 1152, half = rr / 1152;
    bf16 o[4] __attribute__((aligned(8)));
#pragma unroll
    for (int i = 0; i < 4; ++i) {
      int k = k0 + i;
      float v = 0.0f;
      int tt = (r * k) & 2047;
      float ang = (float)tt * (6.283185307179586f / 2048.0f);
      if (half == 0) { if (r <= 1024 && k <= 1024) v = __cosf(ang); }
      else           { if (r <= 1023 && k >= 1 && k <= 1023) v = -__sinf(ang); }
      o[i] = (bf16)v;
    }
    *(uint2*)(Atrig2 + (long)rr * 1088 + k0) = *(const uint2*)o;
  } else if (id < 7056) {              // cast x_dec, 4 elems/thread
    int i = ((id - 2960) * 256 + threadIdx.x) * 4;
    float4 v = *(const float4*)(xdec + i);
    bf16 o[4] __attribute__((aligned(8))) =
        {(bf16)v.x, (bf16)v.y, (bf16)v.z, (bf16)v.w};
    *(uint2*)(xdec_b + i) = *(const uint2*)o;
  } else if (id < 11152) {             // cast x_enc, 4 elems/thread
    int i = ((id - 7056) * 256 + threadIdx.x) * 4;
    float4 v = *(const float4*)(xenc + i);
    bf16 o[4] __attribute__((aligned(8))) =
        {(bf16)v.x, (bf16)v.y, (bf16)v.z, (bf16)v.w};
    *(uint2*)(xenc_b + i) = *(const uint2*)o;
  } else {
    int id2 = id - 11152;
    int kind = id2 >> 10, t = id2 & 1023;
    const float* in; bf16* out; int R, C, rt, ct;
    bool iperm = false, hsel = false; int hh = 0;
    if (kind == 0)      { in = Wq; out = BtQ; R = 2048; C = 512; rt = t >> 4; ct = t & 15; iperm = true; }
    else if (kind == 1) { in = Wk; out = BtK; R = 2048; C = 512; rt = t >> 4; ct = t & 15; iperm = true; }
    else if (kind == 2) { in = Wv; out = BtV; R = 2048; C = 512; rt = t >> 4; ct = t & 15; iperm = true; }
    else if (kind == 3) {              // WoTh[h][n][e] = Wo[4e+h][n]
      int zz = t >> 8, tt = t & 255;
      in = Wo; out = WoTh + (long)zz * 262144;
      R = 512; C = 512; rt = tt >> 4; ct = tt & 15; hsel = true; hh = zz;
    }
    else if (kind == 4) { in = W1; out = W1T; R = 512; C = 2048; rt = t >> 6; ct = t & 63; }
    else                { in = W2; out = W2T; R = 2048; C = 512; rt = t >> 4; ct = t & 15; }
    int c0 = ct * 32, r0 = rt * 32;
    int tx = threadIdx.x & 31, ty = threadIdx.x >> 5;
#pragma unroll
    for (int i = 0; i < 32; i += 8) {
      int r = r0 + ty + i;
      int rr = hsel ? (4 * r + hh) : r;
      tile[ty + i][tx] = (bf16)in[(long)rr * C + (c0 + tx)];
    }
    __syncthreads();
#pragma unroll
    for (int i = 0; i < 32; i += 8) {
      int cc = c0 + ty + i, rr = r0 + tx;
      if (iperm) {  // Bt row from W row h*512+din; cc = e, rr>>9 = h, rr&511 = din
        int e = cc, h = rr >> 9;
        int n = (e & 15) | (h << 4) | ((e >> 4) << 6);
        out[((long)n << 9) + (rr & 511)] = tile[tx][ty + i];
      } else {
        out[(long)cc * R + rr] = tile[tx][ty + i];
      }
    }
  }
}

// Fold Yt [4][512][4096] -> Yf2 [8][512][1088], 4 elems/thread (4352 blocks).
// z<4 cos-fold: k=0 -> Y[0]; k=1024 -> Y[1024]; 0<k<1024 -> Y[k]+Y[2048-k]; else 0.
// z>=4 sin-fold: 1<=k<=1023 -> Y[2048+k]-Y[4096-k]; else 0.
__global__ void __launch_bounds__(256) fold_y(const bf16* __restrict__ Yt,
                                              bf16* __restrict__ Yf2) {
  int idx = blockIdx.x * 256 + threadIdx.x;   // 1114112 = 8*512*272
  int k0 = (idx % 272) * 4;
  int rr = idx / 272;
  int j = rr & 511, z = rr >> 9;
  int b = z & 3, half = z >> 2;
  const bf16* yin = Yt + (long)b * 2097152 + (long)j * 4096;
  bf16 o[4] __attribute__((aligned(8)));
  if (half == 0) {
    bf16 f[4] __attribute__((aligned(8)));
    *(uint2*)f = *(const uint2*)(yin + k0);      // Y[k0..k0+3]
#pragma unroll
    for (int i = 0; i < 4; ++i) {
      int k = k0 + i;
      float v;
      if (k == 0)            v = (float)f[0];
      else if (k == 1024)    v = (float)f[i];
      else if (k < 1024)     v = (float)f[i] + (float)yin[2048 - k];
      else                   v = 0.0f;
      o[i] = (bf16)v;
    }
  } else {
    bf16 f[4] __attribute__((aligned(8)));
    *(uint2*)f = *(const uint2*)(yin + 2048 + k0); // Ys[k0..k0+3]
#pragma unroll
    for (int i = 0; i < 4; ++i) {
      int k = k0 + i;
      float v = 0.0f;
      if (k >= 1 && k <= 1023) v = (float)f[i] - (float)yin[4096 - k];
      o[i] = (bf16)v;
    }
  }
  *(uint2*)(Yf2 + (long)z * 557056 + (long)j * 1088 + k0) = *(const uint2*)o;
}

// ---------------- LN1 with DFT recombination (pairwise vectorized) ----------------
__global__ void __launch_bounds__(256) ln1_kernel(
    const float* __restrict__ xdec, const bf16* __restrict__ CSb,
    const float* __restrict__ g, const float* __restrict__ be,
    bf16* __restrict__ outb) {
  const int row = blockIdx.x, t = threadIdx.x;
  const int b = row >> 11, s = row & 2047;
  const int sp = (s <= 1024) ? s : 2048 - s;
  const float sgn = (s <= 1024) ? 1.0f : -1.0f;
  const bf16* Crow = CSb + ((long)b * 1152 + sp) * 512;
  const bf16* Srow = CSb + ((long)(b + 4) * 1152 + sp) * 512;
  const long base = (long)row * 512;
  float2 xp = *(const float2*)(xdec + base + 2 * t);
  bf16 cp[2] __attribute__((aligned(4)));
  bf16 spv[2] __attribute__((aligned(4)));
  *(uint*)cp = *(const uint*)(Crow + 2 * t);
  *(uint*)spv = *(const uint*)(Srow + 2 * t);
  float v0 = xp.x + (float)cp[0] + sgn * (float)spv[0];
  float v1 = xp.y + (float)cp[1] + sgn * (float)spv[1];
  float sm = v0 + v1, q = v0 * v0 + v1 * v1;
#pragma unroll
  for (int off = 32; off > 0; off >>= 1) {
    sm += __shfl_down(sm, off);
    q += __shfl_down(q, off);
  }
  __shared__ float red[8];
  const int wv = t >> 6, ln = t & 63;
  if (ln == 0) { red[wv] = sm; red[wv + 4] = q; }
  __syncthreads();
  float S = red[0] + red[1] + red[2] + red[3];
  float Q = red[4] + red[5] + red[6] + red[7];
  float mu = S * (1.0f / 512.0f);
  float var = Q * (1.0f / 512.0f) - mu * mu;
  float rstd = rsqrtf(var + 1e-5f);
  float2 gp = *(const float2*)(g + 2 * t);
  float2 bp = *(const float2*)(be + 2 * t);
  bf16 op[2] __attribute__((aligned(4)));
  op[0] = (bf16)(gp.x * (v0 - mu) * rstd + bp.x);
  op[1] = (bf16)(gp.y * (v1 - mu) * rstd + bp.y);
  *(uint*)(outb + base + 2 * t) = *(const uint*)op;
}

// ---------------- generic LayerNorm (bf16+bf16 in, pairwise vectorized) ----------------
template <int WRITE_BF16, int WRITE_F32>
__global__ void __launch_bounds__(256) ln_kernel(
    const bf16* __restrict__ A, const bf16* __restrict__ Bv,
    const float* __restrict__ g, const float* __restrict__ be,
    bf16* __restrict__ outb, float* __restrict__ outf) {
  const int row = blockIdx.x, t = threadIdx.x;
  const long base = (long)row * 512;
  bf16 ap[2] __attribute__((aligned(4)));
  bf16 bpv[2] __attribute__((aligned(4)));
  *(uint*)ap = *(const uint*)(A + base + 2 * t);
  *(uint*)bpv = *(const uint*)(Bv + base + 2 * t);
  float v0 = (float)ap[0] + (float)bpv[0];
  float v1 = (float)ap[1] + (float)bpv[1];
  float s = v0 + v1, q = v0 * v0 + v1 * v1;
#pragma unroll
  for (int off = 32; off > 0; off >>= 1) {
    s += __shfl_down(s, off);
    q += __shfl_down(q, off);
  }
  __shared__ float red[8];
  const int wv = t >> 6, ln = t & 63;
  if (ln == 0) { red[wv] = s; red[wv + 4] = q; }
  __syncthreads();
  float S = red[0] + red[1] + red[2] + red[3];
  float Q = red[4] + red[5] + red[6] + red[7];
  float mu = S * (1.0f / 512.0f);
  float var = Q * (1.0f / 512.0f) - mu * mu;
  float rstd = rsqrtf(var + 1e-5f);
  float2 gp = *(const float2*)(g + 2 * t);
  float2 bp = *(const float2*)(be + 2 * t);
  float o0 = gp.x * (v0 - mu) * rstd + bp.x;
  float o1 = gp.y * (v1 - mu) * rstd + bp.y;
  if (WRITE_BF16) {
    bf16 op[2] __attribute__((aligned(4)));
    op[0] = (bf16)o0; op[1] = (bf16)o1;
    *(uint*)(outb + base + 2 * t) = *(const uint*)op;
  }
  if (WRITE_F32) {
    float2 of; of.x = o0; of.y = o1;
    *(float2*)(outf + base + 2 * t) = of;
  }
}

// ---------------- GEMM body: C = A[M,K] * Bt[N,K]^T (single-buffer m97 K-loop) ---------
// SWIZ: 0 plain; 1 group-by-y; 2 group-by-z; 3 group-by-x. gin = blocks per group.
// ADDR_MODE: 0 plain (sCz*z); 9 gw out (col&15)|(h<<4)|((col>>4)<<6).
// HAS_BIAS: 0 none, 1 bias[sBiasz*z+col].
// AHEAD: 0 A+=sAz*z; 1 A+=sAz*(z&3); 2 A+=sAz*(z>>2).
template <int BN, int ADDR_MODE, int HAS_BIAS, int DO_SELU, int F32OUT, int SWIZ,
          int AHEAD>
static __device__ __forceinline__ void gemm_bt_body(
    int id, bf16* lA, bf16* lB,
    const bf16* __restrict__ A, const bf16* __restrict__ Bt,
    const float* __restrict__ bias, void* __restrict__ Cout,
    int N, int K, long sAz, long sBz, long sBiasz, long sCz,
    int gx, int gy, int gin) {
  int x, y, z;
  {
    if (SWIZ == 0) {
      x = id % gx; int t2 = id / gx; y = t2 % gy; z = t2 / gy;
    } else {
      int xcd = id & 7, r = id >> 3;
      int inner = r % gin, G = xcd + 8 * (r / gin);
      if (SWIZ == 1)      { y = G; x = inner % gx; z = inner / gx; }
      else if (SWIZ == 2) { z = G; x = inner % gx; y = inner / gx; }
      else                { x = G; y = inner % gy; z = inner / gy; }
    }
  }
  A  += (AHEAD == 1) ? sAz * (z & 3) : (AHEAD == 2) ? sAz * (z >> 2) : sAz * z;
  Bt += sBz * z;
  const int m0 = y * 128, n0 = x * BN;
  const int t = threadIdx.x;
  const int lane = t & 63, wave = t >> 6;
  const int srow = t >> 3;
  const int pch  = t & 7;
  const int lch  = pch ^ (srow & 7);   // XOR bank swizzle (global-side)
  const bf16* Ag = A  + (long)(m0 + srow) * K + lch * 8;
  const bf16* Bg = Bt + (long)(n0 + srow) * K + lch * 8;
  bf16* lAp = lA + srow * 64 + pch * 8;
  bf16* lBp = lB + srow * 64 + pch * 8;
  constexpr int MI = (BN == 128) ? 4 : 2;
  const int wm = (BN == 128) ? (wave >> 1) * 64 : wave * 32;
  const int wn = (BN == 128) ? (wave & 1) * 64 : 0;
  const int fr = lane & 15, fq = lane >> 4;

  f32x4 acc[MI][4] = {};

  for (int k0 = 0; k0 < K; k0 += 64) {
    __syncthreads();
#pragma unroll
    for (int i = 0; i < 4; ++i)
      async16(Ag + k0 + (long)(32 * i) * K, lAp + 32 * i * 64);
#pragma unroll
    for (int i = 0; i < BN / 32; ++i)
      async16(Bg + k0 + (long)(32 * i) * K, lBp + 32 * i * 64);
    __syncthreads();
#pragma unroll
    for (int kk = 0; kk < 2; ++kk) {
      bf16x8 av[MI], bfrag[4];
#pragma unroll
      for (int mi = 0; mi < MI; ++mi) {
        int r = wm + mi * 16 + fr;
        int c = (kk * 4 + fq) ^ (r & 7);
        av[mi] = *(const bf16x8*)&lA[r * 64 + c * 8];
      }
#pragma unroll
      for (int ni = 0; ni < 4; ++ni) {
        int r = wn + ni * 16 + fr;
        int c = (kk * 4 + fq) ^ (r & 7);
        bfrag[ni] = *(const bf16x8*)&lB[r * 64 + c * 8];
      }
#pragma unroll
      for (int mi = 0; mi < MI; ++mi)
#pragma unroll
        for (int ni = 0; ni < 4; ++ni)
          acc[mi][ni] = __builtin_amdgcn_mfma_f32_16x16x32_bf16(
              av[mi], bfrag[ni], acc[mi][ni], 0, 0, 0);
    }
  }

  // epilogue: C/D layout col = lane&15, row = (lane>>4)*4 + reg
#pragma unroll
  for (int mi = 0; mi < MI; ++mi) {
#pragma unroll
    for (int ni = 0; ni < 4; ++ni) {
      const int col = n0 + wn + ni * 16 + fr;
      float bias_v = 0.0f;
      if (HAS_BIAS == 1) bias_v = bias[sBiasz * z + col];
      if (ADDR_MODE == 9) {                  // z=b*4+h -> Bt_b[row][(col&15)|(h<<4)|((col>>4)<<6)]
        const int b = z >> 2, h = z & 3;
        const int kidx = (col & 15) | (h << 4) | ((col >> 4) << 6);
#pragma unroll
        for (int r = 0; r < 4; ++r) {
          const int row = m0 + wm + mi * 16 + fq * 4 + r;
          ((bf16*)Cout)[((long)(b * 512 + row)) * 2048 + kidx] =
              (bf16)(acc[mi][ni][r] + bias_v);
        }
      } else {
#pragma unroll
        for (int r = 0; r < 4; ++r) {
          const int row = m0 + wm + mi * 16 + fq * 4 + r;
          float v = acc[mi][ni][r] + bias_v;
          if (DO_SELU) v = v > 0.0f ? 1.0507009873554805f * v
                                    : 1.7580993408473766f * (__expf(v) - 1.0f);
          long addr = sCz * z + (long)row * N + col;
          if (F32OUT) ((float*)Cout)[addr] = v;
          else        ((bf16*)Cout)[addr] = (bf16)v;
        }
      }
    }
  }
}

// standalone wrapper
template <int BN, int ADDR_MODE, int HAS_BIAS, int DO_SELU, int F32OUT, int SWIZ,
          int AHEAD = 0>
__global__ void __launch_bounds__(256, 2) gemm_bt(
    const bf16* __restrict__ A, const bf16* __restrict__ Bt,
    const float* __restrict__ bias, void* __restrict__ Cout,
    int N, int K, long sAz, long sBz, long sBiasz, long sCz,
    int gx, int gy, int gin) {
  __shared__ __align__(16) bf16 lA[128 * 64];
  __shared__ __align__(16) bf16 lB[BN * 64];
  gemm_bt_body<BN, ADDR_MODE, HAS_BIAS, DO_SELU, F32OUT, SWIZ, AHEAD>(
      blockIdx.x, lA, lB, A, Bt, bias, Cout, N, K, sAz, sBz, sBiasz, sCz, gx, gy, gin);
}

// ---------------- Q projection GEMM body (id in [0,1024)) ------------------------------
// BtQ permuted row order -> h == ni: register-axis head-softmax, writes qs2 (kidx).
static __device__ __forceinline__ void qkv_body(
    int id, bf16* lA, bf16* lB,
    const bf16* __restrict__ Aq, const bf16* __restrict__ Aenc,
    const bf16* __restrict__ BQ, const bf16* __restrict__ BK,
    const bf16* __restrict__ BV,
    const float* __restrict__ bq, const float* __restrict__ bk,
    const float* __restrict__ bv,
    bf16* __restrict__ qs2, bf16* __restrict__ ksT, bf16* __restrict__ vsT) {
  const int sid = id & 1023;
  const int xcd = sid & 7, r = sid >> 3;
  const int x = r & 15, y = xcd + 8 * (r >> 4);
  const bf16 *A = Aq, *Bt = BQ; bf16* out = qs2; const float* bias = bq;
  (void)Aenc; (void)BK; (void)BV; (void)bk; (void)bv; (void)ksT; (void)vsT;
  const int K = 512;
  const int m0 = y * 128, n0 = x * 128;
  const int t = threadIdx.x;
  const int lane = t & 63, wave = t >> 6;
  const int srow = t >> 3, pch = t & 7, lch = pch ^ (srow & 7);
  const bf16* Ag = A  + (long)(m0 + srow) * K + lch * 8;
  const bf16* Bg = Bt + (long)(n0 + srow) * K + lch * 8;
  bf16* lAp = lA + srow * 64 + pch * 8;
  bf16* lBp = lB + srow * 64 + pch * 8;
  const int wm = (wave >> 1) * 64, wn = (wave & 1) * 64;
  const int fr = lane & 15, fq = lane >> 4;

  f32x4 acc[4][4] = {};
  for (int k0 = 0; k0 < K; k0 += 64) {
    __syncthreads();
#pragma unroll
    for (int i = 0; i < 4; ++i) {
      async16(Ag + k0 + (long)(32 * i) * K, lAp + 32 * i * 64);
      async16(Bg + k0 + (long)(32 * i) * K, lBp + 32 * i * 64);
    }
    __syncthreads();
#pragma unroll
    for (int kk = 0; kk < 2; ++kk) {
      bf16x8 av[4], bfrag[4];
#pragma unroll
      for (int mi = 0; mi < 4; ++mi) {
        int rr = wm + mi * 16 + fr;
        int c = (kk * 4 + fq) ^ (rr & 7);
        av[mi] = *(const bf16x8*)&lA[rr * 64 + c * 8];
      }
#pragma unroll
      for (int ni = 0; ni < 4; ++ni) {
        int rr = wn + ni * 16 + fr;
        int c = (kk * 4 + fq) ^ (rr & 7);
        bfrag[ni] = *(const bf16x8*)&lB[rr * 64 + c * 8];
      }
#pragma unroll
      for (int mi = 0; mi < 4; ++mi)
#pragma unroll
        for (int ni = 0; ni < 4; ++ni)
          acc[mi][ni] = __builtin_amdgcn_mfma_f32_16x16x32_bf16(
              av[mi], bfrag[ni], acc[mi][ni], 0, 0, 0);
    }
  }

  // h == ni; e = fr + 16*((n0+wn)>>6). Softmax across ni in registers.
  const int ebase = fr + 16 * ((n0 + wn) >> 6);
  const float b0 = bias[ebase], b1 = bias[512 + ebase],
              b2 = bias[1024 + ebase], b3 = bias[1536 + ebase];
#pragma unroll
  for (int mi = 0; mi < 4; ++mi) {
#pragma unroll
    for (int r = 0; r < 4; ++r) {
      const int row = m0 + wm + mi * 16 + fq * 4 + r;
      float v0 = acc[mi][0][r] + b0;
      float v1 = acc[mi][1][r] + b1;
      float v2 = acc[mi][2][r] + b2;
      float v3 = acc[mi][3][r] + b3;
      float m = fmaxf(fmaxf(v0, v1), fmaxf(v2, v3));
      float p0 = __expf(v0 - m), p1 = __expf(v1 - m),
            p2 = __expf(v2 - m), p3 = __expf(v3 - m);
      float rs = 1.0f / (p0 + p1 + p2 + p3);
      const long ob = (long)row * 2048 + n0 + wn + fr;
      out[ob]      = (bf16)(p0 * rs);
      out[ob + 16] = (bf16)(p1 * rs);
      out[ob + 32] = (bf16)(p2 * rs);
      out[ob + 48] = (bf16)(p3 * rs);
    }
  }
}

// ---------------- merged K+V projection body (id in [0,1024)) --------------------------
// Shares the A tile (xenc_b) between K and V: 12 global_load_lds per k-step for 2x
// output, 64 MFMA per barrier pair (dual accumulators). Epilogue runs the proven
// LDS-transpose twice over the 32KiB [lA,lBK) buffer: K (head-softmax) then V.
static __device__ __forceinline__ void kv2_body(
    int sid, bf16* smem,
    const bf16* __restrict__ Aenc, const bf16* __restrict__ BK,
    const bf16* __restrict__ BV,
    const float* __restrict__ bk, const float* __restrict__ bv,
    bf16* __restrict__ ksT, bf16* __restrict__ vsT) {
  const int xcd = sid & 7, r = sid >> 3;
  const int x = r & 15, y = xcd + 8 * (r >> 4);
  const int K = 512;
  const int m0 = y * 128, n0 = x * 128;
  const int t = threadIdx.x;
  const int lane = t & 63, wave = t >> 6;
  const int srow = t >> 3, pch = t & 7, lch = pch ^ (srow & 7);
  bf16* lA  = smem;           // [0,8192) elems
  bf16* lBK = smem + 8192;    // [8192,16384)
  bf16* lBV = smem + 16384;   // [16384,24576)
  const bf16* Ag  = Aenc + (long)(m0 + srow) * K + lch * 8;
  const bf16* BKg = BK   + (long)(n0 + srow) * K + lch * 8;
  const bf16* BVg = BV   + (long)(n0 + srow) * K + lch * 8;
  bf16* lAp  = lA  + srow * 64 + pch * 8;
  bf16* lBKp = lBK + srow * 64 + pch * 8;
  bf16* lBVp = lBV + srow * 64 + pch * 8;
  const int wm = (wave >> 1) * 64, wn = (wave & 1) * 64;
  const int fr = lane & 15, fq = lane >> 4;

  f32x4 accK[4][4] = {}, accV[4][4] = {};
  for (int k0 = 0; k0 < K; k0 += 64) {
    __syncthreads();
#pragma unroll
    for (int i = 0; i < 4; ++i) {
      async16(Ag  + k0 + (long)(32 * i) * K, lAp  + 32 * i * 64);
      async16(BKg + k0 + (long)(32 * i) * K, lBKp + 32 * i * 64);
      async16(BVg + k0 + (long)(32 * i) * K, lBVp + 32 * i * 64);
    }
    __syncthreads();
#pragma unroll
    for (int kk = 0; kk < 2; ++kk) {
      bf16x8 av[4], bkf[4], bvf[4];
#pragma unroll
      for (int mi = 0; mi < 4; ++mi) {
        int rr = wm + mi * 16 + fr;
        int c = (kk * 4 + fq) ^ (rr & 7);
        av[mi] = *(const bf16x8*)&lA[rr * 64 + c * 8];
      }
#pragma unroll
      for (int ni = 0; ni < 4; ++ni) {
        int rr = wn + ni * 16 + fr;
        int c = (kk * 4 + fq) ^ (rr & 7);
        bkf[ni] = *(const bf16x8*)&lBK[rr * 64 + c * 8];
        bvf[ni] = *(const bf16x8*)&lBV[rr * 64 + c * 8];
      }
#pragma unroll
      for (int mi = 0; mi < 4; ++mi)
#pragma unroll
        for (int ni = 0; ni < 4; ++ni) {
          accK[mi][ni] = __builtin_amdgcn_mfma_f32_16x16x32_bf16(
              av[mi], bkf[ni], accK[mi][ni], 0, 0, 0);
          accV[mi][ni] = __builtin_amdgcn_mfma_f32_16x16x32_bf16(
              av[mi], bvf[ni], accV[mi][ni], 0, 0, 0);
        }
    }
  }

  // h == ni; feature index e = fr + 16*((n0+wn)>>6).
  const int ebase = fr + 16 * ((n0 + wn) >> 6);
  const float kb0 = bk[ebase], kb1 = bk[512 + ebase],
              kb2 = bk[1024 + ebase], kb3 = bk[1536 + ebase];
  const float vb0 = bv[ebase], vb1 = bv[512 + ebase],
              vb2 = bv[1024 + ebase], vb3 = bv[1536 + ebase];
  bf16* lT = smem;                       // 32 KiB contiguous (lA+lBK)
  const int bb = m0 >> 11;
  const int s_tile = m0 & 2047;
  const int e_loc = fr + 16 * (wn >> 6); // [0,32)
  const int c = lane & 15, rg = lane >> 4;

  // ---- K (softmax) ----
  __syncthreads();                       // all LDS reads of lA/lBK/lBV done
#pragma unroll
  for (int mi = 0; mi < 4; ++mi) {
    const int s0 = wm + mi * 16 + fq * 4;
    bf16 tmp[4][4] __attribute__((aligned(8)));   // [h][r]
#pragma unroll
    for (int r2 = 0; r2 < 4; ++r2) {
      float v0 = accK[mi][0][r2] + kb0;
      float v1 = accK[mi][1][r2] + kb1;
      float v2 = accK[mi][2][r2] + kb2;
      float v3 = accK[mi][3][r2] + kb3;
      float m = fmaxf(fmaxf(v0, v1), fmaxf(v2, v3));
      float p0 = __expf(v0 - m), p1 = __expf(v1 - m),
            p2 = __expf(v2 - m), p3 = __expf(v3 - m);
      float rs = 1.0f / (p0 + p1 + p2 + p3);
      tmp[0][r2] = (bf16)(p0 * rs); tmp[1][r2] = (bf16)(p1 * rs);
      tmp[2][r2] = (bf16)(p2 * rs); tmp[3][r2] = (bf16)(p3 * rs);
    }
#pragma unroll
    for (int ni = 0; ni < 4; ++ni) {
      const int row = ni * 32 + e_loc;
      const int el = row * 128 + ((((s0 >> 3) ^ (row & 15)) << 3) | (s0 & 7));
      *(uint2*)&lT[el] = *(const uint2*)tmp[ni];
    }
  }
  __syncthreads();
#pragma unroll
  for (int i = 0; i < 8; ++i) {
    const int row = wave * 32 + rg + i * 4;
    const int el = row * 128 + ((c ^ (row & 15)) << 3);
    uint4 v = *(const uint4*)&lT[el];
    const int h = row >> 5, e = (row & 31) + 32 * x;
    *(uint4*)(ksT + ((long)((bb * 4 + h) * 512 + e)) * 2048 + s_tile + c * 8) = v;
  }

  // ---- V (no softmax) ----
  __syncthreads();                       // lT reads complete
#pragma unroll
  for (int mi = 0; mi < 4; ++mi) {
    const int s0 = wm + mi * 16 + fq * 4;
    bf16 tmp[4][4] __attribute__((aligned(8)));
#pragma unroll
    for (int r2 = 0; r2 < 4; ++r2) {
      tmp[0][r2] = (bf16)(accV[mi][0][r2] + vb0);
      tmp[1][r2] = (bf16)(accV[mi][1][r2] + vb1);
      tmp[2][r2] = (bf16)(accV[mi][2][r2] + vb2);
      tmp[3][r2] = (bf16)(accV[mi][3][r2] + vb3);
    }
#pragma unroll
    for (int ni = 0; ni < 4; ++ni) {
      const int row = ni * 32 + e_loc;
      const int el = row * 128 + ((((s0 >> 3) ^ (row & 15)) << 3) | (s0 & 7));
      *(uint2*)&lT[el] = *(const uint2*)tmp[ni];
    }
  }
  __syncthreads();
#pragma unroll
  for (int i = 0; i < 8; ++i) {
    const int row = wave * 32 + rg + i * 4;
    const int el = row * 128 + ((c ^ (row & 15)) << 3);
    uint4 v = *(const uint4*)&lT[el];
    const int h = row >> 5, e = (row & 31) + 32 * x;
    *(uint4*)(vsT + ((long)((bb * 4 + h) * 512 + e)) * 2048 + s_tile + c * 8) = v;
  }
}

// ---------------- fused launches ----------------
// [0,1024): merged K+V projection | [1024,1536): Yt DFT GEMM
__global__ void __launch_bounds__(256, 2) fused_kv_yt(
    const bf16* __restrict__ Aenc, const bf16* __restrict__ BK,
    const bf16* __restrict__ BV,
    const float* __restrict__ bk, const float* __restrict__ bv,
    bf16* __restrict__ ksT, bf16* __restrict__ vsT,
    const bf16* __restrict__ Ttrig, const bf16* __restrict__ xdec_b,
    bf16* __restrict__ Yt) {
  __shared__ __align__(16) bf16 smem[24576];   // 48 KiB
  int id = blockIdx.x;
  if (id < 1024)
    kv2_body(id, smem, Aenc, BK, BV, bk, bv, ksT, vsT);
  else
    gemm_bt_body<128, 0, 0, 0, 0, 3, 0>(id - 1024, smem, smem + 8192,
        Ttrig, xdec_b, nullptr, Yt, 2048, 512, 0L, 1048576L, 0L, 2097152L, 16, 8, 32);
}

// [0,512): gc GEMM | [512,1088): CS GEMM
__global__ void __launch_bounds__(256, 2) fused_gc_cs(
    const bf16* __restrict__ ksT, const bf16* __restrict__ vsT,
    bf16* __restrict__ gc,
    const bf16* __restrict__ Atrig2, const bf16* __restrict__ Yf2,
    bf16* __restrict__ CSb) {
  __shared__ __align__(16) bf16 smem[12288];   // 24 KiB
  int id = blockIdx.x;
  if (id < 512)
    gemm_bt_body<64, 0, 0, 0, 0, 2, 0>(id, smem, smem + 8192,
        ksT, vsT, nullptr, gc, 512, 2048, 1048576L, 1048576L, 0L, 262144L, 8, 4, 32);
  else
    gemm_bt_body<64, 0, 0, 0, 0, 2, 2>(id - 512, smem, smem + 8192,
        Atrig2, Yf2, nullptr, CSb, 512, 1088, 1253376L, 557056L, 0L, 589824L, 8, 9, 72);
}

// [0,1024): Q projection + head-softmax | [1024,1536): gwT GEMM (kidx layout)
__global__ void __launch_bounds__(256, 2) fused_q_gw(
    const bf16* __restrict__ Aq, const bf16* __restrict__ BQ,
    const float* __restrict__ bq, bf16* __restrict__ qs2,
    const bf16* __restrict__ WoTh, const bf16* __restrict__ gc,
    bf16* __restrict__ gwT) {
  __shared__ __align__(16) bf16 smem[16384];   // 32 KiB
  int id = blockIdx.x;
  if (id < 1024)
    qkv_body(id, smem, smem + 8192, Aq, nullptr, BQ, nullptr, nullptr,
             bq, nullptr, nullptr, qs2, nullptr, nullptr);
  else
    gemm_bt_body<64, 9, 0, 0, 0, 2, 1>(id - 1024, smem, smem + 8192,
        WoTh, gc, nullptr, gwT, 512, 512, 262144L, 262144L, 0L, 0L, 8, 4, 32);
}

// ---------------- launcher ----------------
extern "C" void kernel_launch(void* const* d_in, const int* in_sizes, int n_in,
                              void* d_out, int out_size, void* d_ws, size_t ws_size,
                              hipStream_t stream) {
  (void)in_sizes; (void)n_in; (void)out_size; (void)ws_size;
  const float* x_enc = (const float*)d_in[0];
  const float* x_dec = (const float*)d_in[1];
  const float* Wq = (const float*)d_in[2];
  const float* bq = (const float*)d_in[3];
  const float* Wk = (const float*)d_in[4];
  const float* bk = (const float*)d_in[5];
  const float* Wv = (const float*)d_in[6];
  const float* bv = (const float*)d_in[7];
  const float* Wo = (const float*)d_in[8];
  const float* bo = (const float*)d_in[9];
  const float* g1 = (const float*)d_in[10];
  const float* be1 = (const float*)d_in[11];
  const float* g2 = (const float*)d_in[12];
  const float* be2 = (const float*)d_in[13];
  const float* W1 = (const float*)d_in[14];
  const float* b1 = (const float*)d_in[15];
  const float* W2 = (const float*)d_in[16];
  const float* b2 = (const float*)d_in[17];
  const float* g3 = (const float*)d_in[18];
  const float* be3 = (const float*)d_in[19];

  char* ws = (char*)d_ws;
  const size_t MB = 1u << 20;
  // time-disjoint aliasing, peak 255 MiB. Launch order:
  // L1 prep | L2 kv+yt | L3 fold | L4 gc+cs | L5 ln1 | L6 q+gw | L7 attn
  // L8 ln2 | L9 w1 | L10 w2 | L11 ln3
  bf16*  BtQ    = (bf16*) (ws + 0);        // [0,2)   W:L1 R:L6
  bf16*  midb   = (bf16*) (ws + 0);        // [0,32)  W:L9 R:L10
  bf16*  ksT    = (bf16*) (ws + 32 * MB);  // [32,64) W:L2 R:L4
  bf16*  attn_b = (bf16*) (ws + 32 * MB);  // [32,64) W:L7 R:L8
  bf16*  vsT    = (bf16*) (ws + 64 * MB);  // [64,96) W:L2 R:L4
  bf16*  ff_b   = (bf16*) (ws + 72 * MB);  // [72,96) W:L10 R:L11
  bf16*  Atrig2 = (bf16*) (ws + 96 * MB);  // [96,101) W:L1 R:L4
  bf16*  Ttrig  = (bf16*) (ws + 101 * MB); // [101,102) W:L1 R:L2
  bf16*  CSb    = (bf16*) (ws + 102 * MB); // [102,112) W:L4 R:L5
  bf16*  qs2    = (bf16*) (ws + 96 * MB);  // [96,128) W:L6 R:L7
  bf16*  xenc_b = (bf16*) (ws + 128 * MB); // [128,136) W:L1 R:L2
  bf16*  BtK    = (bf16*) (ws + 136 * MB); // [136,138) W:L1 R:L2
  bf16*  BtV    = (bf16*) (ws + 138 * MB); // [138,140) W:L1 R:L2
  bf16*  xd_b   = (bf16*) (ws + 192 * MB); // [192,200) W:L5 R:L6,L8
  bf16*  x2_b   = (bf16*) (ws + 200 * MB); // [200,208) W:L8 R:L9,L11
  bf16*  gwT    = (bf16*) (ws + 208 * MB); // [208,216) W:L6 R:L7
  bf16*  Yt     = (bf16*) (ws + 216 * MB); // [216,232) W:L2 R:L3
  bf16*  gc     = (bf16*) (ws + 216 * MB); // [216,224) W:L4 R:L6 (Yt dead after L3)
  bf16*  Yf2    = (bf16*) (ws + 232 * MB); // [232,241) W:L3 R:L4
  bf16*  WoTh   = (bf16*) (ws + 241 * MB); // [241,243) W:L1 R:L6
  bf16*  W1T    = (bf16*) (ws + 243 * MB); // W:L1 R:L9
  bf16*  W2T    = (bf16*) (ws + 245 * MB); // W:L1 R:L10
  bf16*  xdec_b = (bf16*) (ws + 247 * MB); // [247,255) W:L1 R:L2

  // --- L1: prep (trig + casts x4-vectorized) ---
  prep_all<<<17296, 256, 0, stream>>>(x_dec, x_enc, Ttrig, Atrig2, xdec_b, xenc_b,
                                      Wq, Wk, Wv, Wo, W1, W2,
                                      BtQ, BtK, BtV, WoTh, W1T, W2T);

  // --- L2: merged K+V projection (A-tile shared)  ∥  Yt DFT GEMM ---
  fused_kv_yt<<<1536, 256, 0, stream>>>(xenc_b, BtK, BtV, bk, bv, ksT, vsT,
                                        Ttrig, xdec_b, Yt);

  // --- L3: fold (4 elems/thread) ---
  fold_y<<<4352, 256, 0, stream>>>(Yt, Yf2);

  // --- L4: gc GEMM  ∥  CS GEMM ---
  fused_gc_cs<<<1088, 256, 0, stream>>>(ksT, vsT, gc, Atrig2, Yf2, CSb);

  // --- L5: LN1 ---
  ln1_kernel<<<8192, 256, 0, stream>>>(x_dec, CSb, g1, be1, xd_b);

  // --- L6: Q projection+softmax  ∥  gwT ---
  fused_q_gw<<<1536, 256, 0, stream>>>(xd_b, BtQ, bq, qs2, WoTh, gc, gwT);

  // --- L7: attn = qs2 . gwT^T + bo ---
  gemm_bt<64, 0, 1, 0, 0, 1><<<512, 256, 0, stream>>>(
      qs2, gwT, bo, attn_b, 512, 2048, 4194304L, 1048576L, 0L, 1048576L, 8, 16, 32);
  // --- L8: LN2 ---
  ln_kernel<1, 0><<<8192, 256, 0, stream>>>(
      xd_b, attn_b, g2, be2, x2_b, nullptr);

  // --- L9: FFN W1 + SELU ---
  gemm_bt<128, 0, 1, 1, 0, 1><<<1024, 256, 0, stream>>>(
      x2_b, W1T, b1, midb, 2048, 512, 0L, 0L, 0L, 0L, 16, 64, 16);
  // --- L10: FFN W2 ---
  gemm_bt<64, 0, 1, 0, 0, 1><<<512, 256, 0, stream>>>(
      midb, W2T, b2, ff_b, 512, 2048, 0L, 0L, 0L, 0L, 8, 64, 8);
  // --- L11: LN3 -> output (f32) ---
  ln_kernel<0, 1><<<8192, 256, 0, stream>>>(
      x2_b, ff_b, g3, be3, nullptr, (float*)d_out);
}